// Round 3
// baseline (2875.007 us; speedup 1.0000x reference)
//
#include <hip/hip_runtime.h>

typedef unsigned short u16;
typedef unsigned int u32;

// Problem constants
#define BB 8
#define NQ 1024
#define NK 256
#define CC 48
#define HH 8

// Inputs are float32; OUTPUT is float32 (reference computes in fp32).
// Workspace intermediates are bf16 (2% relative threshold gives headroom).
__device__ __forceinline__ float bf2f(u16 u) {
  union { u32 i; float f; } v; v.i = ((u32)u) << 16; return v.f;
}
__device__ __forceinline__ u16 f2bf(float f) {
  union { u32 i; float f; } v; v.f = f;
  u32 i = v.i;
  return (u16)((i + 0x7FFFu + ((i >> 16) & 1u)) >> 16);
}

__device__ __forceinline__ float softplusf(float d) {
  return (d > 20.f) ? d : log1pf(__expf(d));
}

constexpr float INV_S384 = 0.05103103630798288f; // 1/sqrt(8*48)

// ---------------------------------------------------------------------------
// Kernel A: kv = equi_linear(vision, Wkv, bkv); write packed k_sel (11 comps,
// unscaled), v (16 comps), and per-key score bias = -lambda_h/48 * k2.
// grid = B*NK blocks, 256 threads.
// ---------------------------------------------------------------------------
__global__ __launch_bounds__(256) void kv_kernel(
    const float* __restrict__ vis, const float* __restrict__ Wkv,
    const float* __restrict__ bkv, const float* __restrict__ daa,
    u16* __restrict__ ksel, float* __restrict__ kbias, u16* __restrict__ vws) {
  const int row = blockIdx.x;          // b*NK + n
  const int b = row >> 8, n = row & 255;
  const int t = threadIdx.x;
  __shared__ __align__(16) float x[768];
  __shared__ float k2h[HH];
  for (int i = t; i < 768; i += 256) x[i] = vis[(size_t)row * 768 + i];
  if (t < HH) k2h[t] = 0.f;
  __syncthreads();

  for (int o = t; o < 768; o += 256) {
    float acc[16];
#pragma unroll
    for (int j = 0; j < 16; j++) acc[j] = 0.f;
    acc[0] = bkv[o];
    const float* w0 = Wkv + (size_t)(0 * 768 + o) * 48;
    const float* w1 = Wkv + (size_t)(1 * 768 + o) * 48;
    const float* w2 = Wkv + (size_t)(2 * 768 + o) * 48;
    const float* w3 = Wkv + (size_t)(3 * 768 + o) * 48;
    const float* w4 = Wkv + (size_t)(4 * 768 + o) * 48;
    for (int i = 0; i < 48; i++) {
      const float4* xp = (const float4*)&x[i * 16];
      float4 a0 = xp[0], a1 = xp[1], a2 = xp[2], a3 = xp[3];
      float f0 = w0[i], f1 = w1[i], f2 = w2[i], f3 = w3[i], f4 = w4[i];
      acc[0] += a0.x * f0;
      acc[1] += a0.y * f1; acc[2] += a0.z * f1; acc[3] += a0.w * f1;
      acc[4] += a1.x * f1;
      acc[5] += a1.y * f2; acc[6] += a1.z * f2; acc[7] += a1.w * f2;
      acc[8] += a2.x * f2; acc[9] += a2.y * f2; acc[10] += a2.z * f2;
      acc[11] += a2.w * f3; acc[12] += a3.x * f3; acc[13] += a3.y * f3;
      acc[14] += a3.z * f3;
      acc[15] += a3.w * f4;
    }
    if (o < 384) {  // k half
      int h = o / 48, c = o - h * 48;
      size_t kb_ = ((size_t)(b * HH + h) * NK + n) * 528;
      // inner slots 0..7 = j {0,2,3,4,8,9,10,14}; point slots 8..10 = j {11,12,13}
      ksel[kb_ + 0 * 48 + c] = f2bf(acc[0]);
      ksel[kb_ + 1 * 48 + c] = f2bf(acc[2]);
      ksel[kb_ + 2 * 48 + c] = f2bf(acc[3]);
      ksel[kb_ + 3 * 48 + c] = f2bf(acc[4]);
      ksel[kb_ + 4 * 48 + c] = f2bf(acc[8]);
      ksel[kb_ + 5 * 48 + c] = f2bf(acc[9]);
      ksel[kb_ + 6 * 48 + c] = f2bf(acc[10]);
      ksel[kb_ + 7 * 48 + c] = f2bf(acc[14]);
      ksel[kb_ + 8 * 48 + c] = f2bf(acc[11]);
      ksel[kb_ + 9 * 48 + c] = f2bf(acc[12]);
      ksel[kb_ + 10 * 48 + c] = f2bf(acc[13]);
      atomicAdd(&k2h[h], acc[11] * acc[11] + acc[12] * acc[12] + acc[13] * acc[13]);
    } else {        // v half
      int o2 = o - 384;
      int h = o2 / 48, c = o2 - h * 48;
      size_t vb = ((size_t)(b * HH + h) * NK + n) * 768 + (size_t)c * 16;
#pragma unroll
      for (int j = 0; j < 16; j++) vws[vb + j] = f2bf(acc[j]);
    }
  }
  __syncthreads();
  if (t < HH) {
    float lam = softplusf(daa[t]);
    kbias[(size_t)(b * HH + t) * NK + n] = -(lam / 48.f) * k2h[t];
  }
}

// ---------------------------------------------------------------------------
// Kernel B: normed = equi_rms_norm(hidden, ln_w); q = equi_linear(normed, Wq, bq);
// write packed q_sel with score scaling folded in (inner * 1/sqrt(384),
// point * 2*lambda_h/48).  grid = B*NQ blocks, 256 threads.
// ---------------------------------------------------------------------------
__global__ __launch_bounds__(256) void q_kernel(
    const float* __restrict__ hidden, const float* __restrict__ lnw,
    const float* __restrict__ Wq, const float* __restrict__ bq,
    const float* __restrict__ daa, u16* __restrict__ qsel) {
  const int row = blockIdx.x;  // b*NQ + n
  const int b = row >> 10, n = row & 1023;
  const int t = threadIdx.x;
  __shared__ __align__(16) float x[768];
  __shared__ float ssum[4];
  __shared__ float sscale;
  float ps = 0.f;
  for (int i = t; i < 768; i += 256) {
    float v = hidden[(size_t)row * 768 + i];
    x[i] = v; ps += v * v;
  }
#pragma unroll
  for (int off = 32; off; off >>= 1) ps += __shfl_down(ps, off);
  if ((t & 63) == 0) ssum[t >> 6] = ps;
  __syncthreads();
  if (t == 0)
    sscale = rsqrtf((ssum[0] + ssum[1] + ssum[2] + ssum[3]) * (1.f / 48.f) + 1e-6f);
  __syncthreads();
  float scl = sscale;
  for (int i = t; i < 768; i += 256) x[i] *= scl * lnw[i >> 4];
  __syncthreads();

  for (int o = t; o < 384; o += 256) {
    float acc[16];
#pragma unroll
    for (int j = 0; j < 16; j++) acc[j] = 0.f;
    acc[0] = bq[o];
    const float* w0 = Wq + (size_t)(0 * 384 + o) * 48;
    const float* w1 = Wq + (size_t)(1 * 384 + o) * 48;
    const float* w2 = Wq + (size_t)(2 * 384 + o) * 48;
    const float* w3 = Wq + (size_t)(3 * 384 + o) * 48;
    const float* w4 = Wq + (size_t)(4 * 384 + o) * 48;
    for (int i = 0; i < 48; i++) {
      const float4* xp = (const float4*)&x[i * 16];
      float4 a0 = xp[0], a1 = xp[1], a2 = xp[2], a3 = xp[3];
      float f0 = w0[i], f1 = w1[i], f2 = w2[i], f3 = w3[i], f4 = w4[i];
      acc[0] += a0.x * f0;
      acc[1] += a0.y * f1; acc[2] += a0.z * f1; acc[3] += a0.w * f1;
      acc[4] += a1.x * f1;
      acc[5] += a1.y * f2; acc[6] += a1.z * f2; acc[7] += a1.w * f2;
      acc[8] += a2.x * f2; acc[9] += a2.y * f2; acc[10] += a2.z * f2;
      acc[11] += a2.w * f3; acc[12] += a3.x * f3; acc[13] += a3.y * f3;
      acc[14] += a3.z * f3;
      acc[15] += a3.w * f4;
    }
    int h = o / 48, c = o - h * 48;
    float lam = softplusf(daa[h]);
    float pc = 2.f * lam / 48.f;
    size_t qb = ((size_t)(b * HH + h) * NQ + n) * 528;
    qsel[qb + 0 * 48 + c] = f2bf(acc[0] * INV_S384);
    qsel[qb + 1 * 48 + c] = f2bf(acc[2] * INV_S384);
    qsel[qb + 2 * 48 + c] = f2bf(acc[3] * INV_S384);
    qsel[qb + 3 * 48 + c] = f2bf(acc[4] * INV_S384);
    qsel[qb + 4 * 48 + c] = f2bf(acc[8] * INV_S384);
    qsel[qb + 5 * 48 + c] = f2bf(acc[9] * INV_S384);
    qsel[qb + 6 * 48 + c] = f2bf(acc[10] * INV_S384);
    qsel[qb + 7 * 48 + c] = f2bf(acc[14] * INV_S384);
    qsel[qb + 8 * 48 + c] = f2bf(acc[11] * pc);
    qsel[qb + 9 * 48 + c] = f2bf(acc[12] * pc);
    qsel[qb + 10 * 48 + c] = f2bf(acc[13] * pc);
  }
}

// ---------------------------------------------------------------------------
// Kernel C: fused attention per (q-tile=16, h, b).
// scores = q_sel . k_sel + kbias  (528-dot, c-chunked through LDS, 4q x 4k regs)
// softmax over 256 keys in LDS; ctx = P @ V with V streamed coalesced.
// grid = (NQ/16, H, B), 256 threads.
// ---------------------------------------------------------------------------
__global__ __launch_bounds__(256) void attn_kernel(
    const u16* __restrict__ qsel, const u16* __restrict__ ksel,
    const float* __restrict__ kbias, const u16* __restrict__ vws,
    u16* __restrict__ ctx) {
  const int qt = blockIdx.x, h = blockIdx.y, b = blockIdx.z;
  const int t = threadIdx.x;
  const int q0 = qt * 16;
  __shared__ __align__(16) float qch[16 * 49];   // q chunk, pad 49 vs banks
  __shared__ __align__(16) float kch[256 * 49];  // k chunk
  __shared__ __align__(16) float sp[16 * 256];   // scores -> unnormalized probs
  __shared__ float rsum[16];
  __shared__ float kb[256];

  const size_t bh = (size_t)(b * HH + h);
  const u16* qg = qsel + (bh * NQ + q0) * 528;
  const u16* kg_ = ksel + bh * NK * 528;
  const float* kbg = kbias + bh * NK;
  const u16* vgb = vws + bh * NK * 768;

  kb[t] = kbg[t];

  const int qgi = t >> 6;  // 0..3  (wave-uniform)
  const int kgi = t & 63;  // 0..63
  float acc[4][4];
#pragma unroll
  for (int r = 0; r < 4; r++)
#pragma unroll
    for (int s = 0; s < 4; s++) acc[r][s] = 0.f;

  for (int slot = 0; slot < 11; slot++) {
    __syncthreads();
    for (int idx = t; idx < 16 * 48; idx += 256) {
      int r = idx / 48, c2 = idx - r * 48;
      qch[r * 49 + c2] = bf2f(qg[(size_t)r * 528 + slot * 48 + c2]);
    }
    for (int idx = t; idx < 256 * 48; idx += 256) {
      int r = idx / 48, c2 = idx - r * 48;
      kch[r * 49 + c2] = bf2f(kg_[(size_t)r * 528 + slot * 48 + c2]);
    }
    __syncthreads();
#pragma unroll 4
    for (int cc = 0; cc < 48; cc++) {
      float qv[4], kv[4];
#pragma unroll
      for (int r = 0; r < 4; r++) qv[r] = qch[(qgi * 4 + r) * 49 + cc];  // broadcast
#pragma unroll
      for (int s = 0; s < 4; s++) kv[s] = kch[(kgi + 64 * s) * 49 + cc]; // 2-way max
#pragma unroll
      for (int r = 0; r < 4; r++)
#pragma unroll
        for (int s = 0; s < 4; s++) acc[r][s] += qv[r] * kv[s];
    }
  }
  __syncthreads();
#pragma unroll
  for (int r = 0; r < 4; r++)
#pragma unroll
    for (int s = 0; s < 4; s++) {
      int k = kgi + 64 * s;
      sp[(qgi * 4 + r) * 256 + k] = acc[r][s] + kb[k];
    }
  __syncthreads();
  // softmax over k (16 threads per q-row, shfl within 16-lane groups)
  {
    int rrow = t >> 4, col = t & 15;
    float vals[16];
    float m = -1e30f;
#pragma unroll
    for (int i = 0; i < 16; i++) {
      vals[i] = sp[rrow * 256 + col + 16 * i];
      m = fmaxf(m, vals[i]);
    }
#pragma unroll
    for (int off = 8; off; off >>= 1) m = fmaxf(m, __shfl_xor(m, off, 16));
    float s_ = 0.f;
#pragma unroll
    for (int i = 0; i < 16; i++) {
      float e = __expf(vals[i] - m);
      s_ += e;
      sp[rrow * 256 + col + 16 * i] = e;
    }
#pragma unroll
    for (int off = 8; off; off >>= 1) s_ += __shfl_xor(s_, off, 16);
    if (col == 0) rsum[rrow] = s_;
  }
  __syncthreads();
  // ctx: each thread owns 3 d-columns (d = t, t+256, t+512) for all 16 q
  float o0[16], o1[16], o2[16];
#pragma unroll
  for (int q = 0; q < 16; q++) { o0[q] = 0.f; o1[q] = 0.f; o2[q] = 0.f; }
  for (int k = 0; k < 256; k++) {
    const u16* vr = vgb + (size_t)k * 768;
    float v0 = bf2f(vr[t]), v1 = bf2f(vr[t + 256]), v2 = bf2f(vr[t + 512]);
#pragma unroll
    for (int q = 0; q < 16; q++) {
      float p = sp[q * 256 + k];  // broadcast
      o0[q] += p * v0; o1[q] += p * v1; o2[q] += p * v2;
    }
  }
#pragma unroll
  for (int q = 0; q < 16; q++) {
    float inv = 1.f / rsum[q];
    size_t base = ((size_t)(b * NQ + q0 + q)) * 6144 + (size_t)h * 768;
    ctx[base + t] = f2bf(o0[q] * inv);
    ctx[base + t + 256] = f2bf(o1[q] * inv);
    ctx[base + t + 512] = f2bf(o2[q] * inv);
  }
}

// ---------------------------------------------------------------------------
// Kernel D: y = hidden + equi_linear(ctx, Wo, bo).  grid = B*NQ, 256 threads.
// ctx row transposed into LDS [j][i] (stride 388) for vector reads.
// OUTPUT IS FP32.
// ---------------------------------------------------------------------------
__global__ __launch_bounds__(256) void out_kernel(
    const u16* __restrict__ ctx, const float* __restrict__ Wo,
    const float* __restrict__ bo, const float* __restrict__ hidden,
    float* __restrict__ out) {
  const int row = blockIdx.x;
  const int t = threadIdx.x;
  __shared__ __align__(16) float xt[16 * 388];
  for (int idx = t; idx < 6144; idx += 256) {
    int i = idx >> 4, j = idx & 15;
    xt[j * 388 + i] = bf2f(ctx[(size_t)row * 6144 + idx]);
  }
  __syncthreads();
  const int j = t & 15;
  const int obase = t >> 4;  // 0..15
  constexpr int GR[16] = {0, 1, 1, 1, 1, 2, 2, 2, 2, 2, 2, 3, 3, 3, 3, 4};
  const int g = GR[j];
  const float4* xr = (const float4*)&xt[j * 388];
#pragma unroll
  for (int pass = 0; pass < 3; pass++) {
    int o = pass * 16 + obase;
    const float* wr = Wo + (size_t)(g * 48 + o) * 384;
    const float4* wv = (const float4*)wr;
    float acc = (j == 0) ? bo[o] : 0.f;
    for (int ib = 0; ib < 48; ib++) {
      float4 wa = wv[ib * 2], wb = wv[ib * 2 + 1];
      float4 xa = xr[ib * 2], xb = xr[ib * 2 + 1];
      acc += xa.x * wa.x + xa.y * wa.y + xa.z * wa.z + xa.w * wa.w;
      acc += xb.x * wb.x + xb.y * wb.y + xb.z * wb.z + xb.w * wb.w;
    }
    size_t oi = (size_t)row * 768 + (size_t)o * 16 + j;  // = row*768 + pass*256 + t
    out[oi] = acc + hidden[oi];
  }
}

// ---------------------------------------------------------------------------
extern "C" void kernel_launch(void* const* d_in, const int* in_sizes, int n_in,
                              void* d_out, int out_size, void* d_ws, size_t ws_size,
                              hipStream_t stream) {
  const float* hidden = (const float*)d_in[0];
  const float* vis = (const float*)d_in[1];
  const float* lnw = (const float*)d_in[2];
  const float* Wq = (const float*)d_in[3];
  const float* bq = (const float*)d_in[4];
  const float* Wkv = (const float*)d_in[5];
  const float* bkv = (const float*)d_in[6];
  const float* Wo = (const float*)d_in[7];
  const float* bo = (const float*)d_in[8];
  const float* daa = (const float*)d_in[9];
  float* out = (float*)d_out;

  char* ws = (char*)d_ws;
  size_t off = 0;
  auto carve = [&](size_t bytes) -> void* {
    void* p = ws + off;
    off += (bytes + 255) & ~(size_t)255;
    return p;
  };
  u16* qsel = (u16*)carve((size_t)BB * HH * NQ * 528 * 2);   // 69.2 MB
  u16* ksel = (u16*)carve((size_t)BB * HH * NK * 528 * 2);   // 17.3 MB
  u16* vws = (u16*)carve((size_t)BB * HH * NK * 768 * 2);    // 25.2 MB
  float* kbias = (float*)carve((size_t)BB * HH * NK * 4);    // 64 KB
  u16* ctx = (u16*)carve((size_t)BB * NQ * 384 * 16 * 2);    // 100.7 MB

  kv_kernel<<<BB * NK, 256, 0, stream>>>(vis, Wkv, bkv, daa, ksel, kbias, vws);
  q_kernel<<<BB * NQ, 256, 0, stream>>>(hidden, lnw, Wq, bq, daa, qsel);
  attn_kernel<<<dim3(NQ / 16, HH, BB), 256, 0, stream>>>(qsel, ksel, kbias, vws, ctx);
  out_kernel<<<BB * NQ, 256, 0, stream>>>(ctx, Wo, bo, hidden, out);
}

// Round 4
// 1502.988 us; speedup vs baseline: 1.9129x; 1.9129x over previous
//
#include <hip/hip_runtime.h>

typedef unsigned short u16;
typedef unsigned int u32;
typedef unsigned long long u64;

typedef float f32x4 __attribute__((ext_vector_type(4)));
typedef short bf16x8 __attribute__((ext_vector_type(8)));

#define BB 8
#define NQ 1024
#define NK 256
#define CC 48
#define HH 8
#define KD 544   // padded score-dot length (11*48=528 -> 544 = 17*32)

__device__ __forceinline__ float bf2f(u16 u) {
  union { u32 i; float f; } v; v.i = ((u32)u) << 16; return v.f;
}
__device__ __forceinline__ u16 f2bf(float f) {
  union { u32 i; float f; } v; v.f = f;
  u32 i = v.i;
  return (u16)((i + 0x7FFFu + ((i >> 16) & 1u)) >> 16);
}
__device__ __forceinline__ float softplusf(float d) {
  return (d > 20.f) ? d : log1pf(__expf(d));
}

// packed nibble tables indexed by component c=0..15
// slot: position in packed 11-slot score vector (15 = unused component)
#define SLOT_TAB 0xF7A98654FFF321F0ULL
// grade: GRADE_IDX from reference
#define GRADE_TAB 0x4333322222211110ULL
__device__ __forceinline__ int slot_of(int c) { return (int)((SLOT_TAB >> (c * 4)) & 15ULL); }
__device__ __forceinline__ int grade_of(int c) { return (int)((GRADE_TAB >> (c * 4)) & 15ULL); }

constexpr float INV_S384 = 0.05103103630798288f; // 1/sqrt(8*48)

// ---------------------------------------------------------------------------
// q projection: RMS-norm + equi_linear(Wq) -> packed/scaled qsel rows (KD u16)
// block = 16 rows, 256 threads; thread = (row r = t>>4, component c = t&15)
// x held in 48 registers; weights staged per 32-o chunk in LDS (broadcast reads)
// ---------------------------------------------------------------------------
__global__ __launch_bounds__(256) void q_kernel(
    const float* __restrict__ hidden, const float* __restrict__ lnw,
    const float* __restrict__ Wq, const float* __restrict__ bq,
    const float* __restrict__ daa, u16* __restrict__ qsel) {
  const int row0 = blockIdx.x * 16;
  const int b = row0 >> 10;
  const int n0 = row0 & 1023;
  const int t = threadIdx.x;
  __shared__ __align__(16) float xs[16 * 768];   // 48 KB
  __shared__ __align__(16) float ws[5 * 32 * 48]; // 30 KB
  __shared__ float srms[16];
  __shared__ float slnw[48];
  __shared__ float spc[8];

  for (int idx = t; idx < 16 * 768; idx += 256)
    xs[idx] = hidden[(size_t)row0 * 768 + idx];
  if (t < 48) slnw[t] = lnw[t];
  if (t < 8) spc[t] = 2.f * softplusf(daa[t]) / 48.f;
  __syncthreads();
  {
    int r = t >> 4, l = t & 15;
    float s = 0.f;
    for (int m = 0; m < 48; m++) { float v = xs[r * 768 + l + 16 * m]; s += v * v; }
#pragma unroll
    for (int off = 8; off; off >>= 1) s += __shfl_xor(s, off, 16);
    if (l == 0) srms[r] = rsqrtf(s * (1.f / 48.f) + 1e-6f);
  }
  __syncthreads();
  const int r = t >> 4, c = t & 15;
  float xr[48];
  {
    float sc = srms[r];
#pragma unroll
    for (int i = 0; i < 48; i++) xr[i] = xs[r * 768 + i * 16 + c] * sc * slnw[i];
  }
  const int slot = slot_of(c);
  const int gc = grade_of(c);

  for (int ch = 0; ch < 12; ch++) {
    const int o0 = ch * 32;
    __syncthreads();
    for (int idx = t; idx < 5 * 32 * 48; idx += 256) {
      int g = idx / 1536;
      int rem = idx - g * 1536;
      int ol = rem / 48, i = rem - ol * 48;
      ws[idx] = Wq[(size_t)(g * 384 + o0 + ol) * 48 + i];
    }
    __syncthreads();
    if (slot < 15) {
#pragma unroll 4
      for (int ol = 0; ol < 32; ol++) {
        const int o = o0 + ol;
        const float* wrow = &ws[(gc * 32 + ol) * 48];
        float acc = 0.f;
#pragma unroll
        for (int i = 0; i < 48; i += 4) {
          float4 wv = *(const float4*)(wrow + i);
          acc += xr[i] * wv.x + xr[i + 1] * wv.y + xr[i + 2] * wv.z + xr[i + 3] * wv.w;
        }
        int hh = o / 48, oc = o - hh * 48;
        if (c == 0) acc += bq[o];
        float scale = (slot < 8) ? INV_S384 : spc[hh];
        qsel[((size_t)(b * HH + hh) * NQ + n0 + r) * KD + slot * 48 + oc] = f2bf(acc * scale);
      }
    }
  }
  // zero pad [528,544) for every (h,row)
  for (int m = t; m < 8 * 16 * 16; m += 256) {
    int hh = m >> 8;
    int rr = (m >> 4) & 15;
    int pd = m & 15;
    qsel[((size_t)(b * HH + hh) * NQ + n0 + rr) * KD + 528 + pd] = 0;
  }
}

// ---------------------------------------------------------------------------
// kv projection: equi_linear(Wkv) -> ksel (packed, unscaled, KD rows),
// vT[bh][d=48c*16+j][key] (bf16, transposed for PV B-frags), kbias=-lam/48*k2
// block = 16 rows, 256 threads
// ---------------------------------------------------------------------------
__global__ __launch_bounds__(256) void kv_kernel(
    const float* __restrict__ vis, const float* __restrict__ Wkv,
    const float* __restrict__ bkv, const float* __restrict__ daa,
    u16* __restrict__ ksel, float* __restrict__ kbias, u16* __restrict__ vT) {
  const int row0 = blockIdx.x * 16;
  const int b = row0 >> 8;
  const int n0 = row0 & 255;
  const int t = threadIdx.x;
  __shared__ __align__(16) float xs[16 * 768];
  __shared__ __align__(16) float ws[5 * 32 * 48];
  __shared__ float k2s[16 * 8];
  __shared__ float slam[8];

  for (int idx = t; idx < 16 * 768; idx += 256)
    xs[idx] = vis[(size_t)row0 * 768 + idx];
  if (t < 8) slam[t] = softplusf(daa[t]);
  if (t < 128) k2s[t] = 0.f;
  __syncthreads();
  const int r = t >> 4, c = t & 15;
  float xr[48];
#pragma unroll
  for (int i = 0; i < 48; i++) xr[i] = xs[r * 768 + i * 16 + c];
  const int slot = slot_of(c);
  const int gc = grade_of(c);
  const bool is_pt = (c == 11 || c == 12 || c == 13);

  for (int ch = 0; ch < 24; ch++) {
    const int o0 = ch * 32;
    __syncthreads();
    for (int idx = t; idx < 5 * 32 * 48; idx += 256) {
      int g = idx / 1536;
      int rem = idx - g * 1536;
      int ol = rem / 48, i = rem - ol * 48;
      ws[idx] = Wkv[(size_t)(g * 768 + o0 + ol) * 48 + i];
    }
    __syncthreads();
#pragma unroll 4
    for (int ol = 0; ol < 32; ol++) {
      const int o = o0 + ol;
      const float* wrow = &ws[(gc * 32 + ol) * 48];
      float acc = 0.f;
#pragma unroll
      for (int i = 0; i < 48; i += 4) {
        float4 wv = *(const float4*)(wrow + i);
        acc += xr[i] * wv.x + xr[i + 1] * wv.y + xr[i + 2] * wv.z + xr[i + 3] * wv.w;
      }
      if (c == 0) acc += bkv[o];
      if (o < 384) {
        int hh = o / 48, oc = o - hh * 48;
        if (slot < 15)
          ksel[((size_t)(b * HH + hh) * NK + n0 + r) * KD + slot * 48 + oc] = f2bf(acc);
        if (is_pt) atomicAdd(&k2s[r * 8 + hh], acc * acc);
      } else {
        int o2 = o - 384;
        int hh = o2 / 48, oc = o2 - hh * 48;
        vT[((size_t)(b * HH + hh)) * 768 * 256 + (size_t)(oc * 16 + c) * 256 + n0 + r] = f2bf(acc);
      }
    }
  }
  __syncthreads();
  if (t < 128) {
    int rr = t >> 3, hh = t & 7;
    kbias[((size_t)(b * HH + hh)) * NK + n0 + rr] = -(slam[hh] / 48.f) * k2s[rr * 8 + hh];
  }
  for (int m = t; m < 8 * 16 * 16; m += 256) {
    int hh = m >> 8;
    int rr = (m >> 4) & 15;
    int pd = m & 15;
    ksel[((size_t)(b * HH + hh) * NK + n0 + rr) * KD + 528 + pd] = 0;
  }
}

// ---------------------------------------------------------------------------
// MFMA attention: block = (32 q rows, h, b), 256 threads (4 waves).
// Wave w: keys [w*64, w*64+64) for scores; d in [w*192,(w+1)*192) for PV.
// scores via mfma_f32_16x16x32_bf16 (Q row-major A-frag, K row-major B-frag);
// softmax in LDS (f32 scores -> bf16 P in A-layout); PV via MFMA with vT.
// ---------------------------------------------------------------------------
#define SPW 260   // f32 score row stride (16B aligned, <=2-way banks)
#define SPBW 264  // u16 P row stride (16B aligned, 2-way banks)
__global__ __launch_bounds__(256) void attn_kernel(
    const u16* __restrict__ qsel, const u16* __restrict__ ksel,
    const float* __restrict__ kbias, const u16* __restrict__ vT,
    u16* __restrict__ ctx) {
  const int qt = blockIdx.x, h = blockIdx.y, b = blockIdx.z;
  const int t = threadIdx.x;
  const int w = t >> 6;
  const int lane = t & 63;
  const int m16 = lane & 15;
  const int quad = lane >> 4;

  __shared__ __align__(16) float sp[32 * SPW];   // 33.3 KB
  __shared__ __align__(16) u16 spb[32 * SPBW];   // 16.9 KB
  __shared__ float kb[256];
  __shared__ float inv[32];

  const size_t bh = (size_t)(b * HH + h);
  const int n0 = qt * 32;
  const u16* qg = qsel + (bh * NQ + n0) * KD;
  const u16* kg = ksel + bh * NK * KD;
  const u16* vg = vT + bh * 768 * 256;

  kb[t] = kbias[bh * NK + t];

  // ---- scores: S[32][256] ----
  f32x4 sacc[2][4];
#pragma unroll
  for (int mt = 0; mt < 2; mt++)
#pragma unroll
    for (int nt = 0; nt < 4; nt++) sacc[mt][nt] = (f32x4)0.f;

  for (int ks = 0; ks < 17; ks++) {
    bf16x8 qa0 = *(const bf16x8*)(qg + (size_t)(0 * 16 + m16) * KD + ks * 32 + quad * 8);
    bf16x8 qa1 = *(const bf16x8*)(qg + (size_t)(1 * 16 + m16) * KD + ks * 32 + quad * 8);
#pragma unroll
    for (int nt = 0; nt < 4; nt++) {
      bf16x8 kf = *(const bf16x8*)(kg + (size_t)(w * 64 + nt * 16 + m16) * KD + ks * 32 + quad * 8);
      sacc[0][nt] = __builtin_amdgcn_mfma_f32_16x16x32_bf16(qa0, kf, sacc[0][nt], 0, 0, 0);
      sacc[1][nt] = __builtin_amdgcn_mfma_f32_16x16x32_bf16(qa1, kf, sacc[1][nt], 0, 0, 0);
    }
  }
#pragma unroll
  for (int mt = 0; mt < 2; mt++)
#pragma unroll
    for (int nt = 0; nt < 4; nt++)
#pragma unroll
      for (int rr = 0; rr < 4; rr++)
        sp[(mt * 16 + quad * 4 + rr) * SPW + w * 64 + nt * 16 + m16] = sacc[mt][nt][rr];
  __syncthreads();

  // ---- softmax over 256 keys per row; write P (bf16, A-layout) ----
  {
    const int rr = t >> 3, cg = t & 7;
    float vals[32];
    float mx = -1e30f;
#pragma unroll
    for (int i = 0; i < 32; i++) {
      int k = cg + 8 * i;
      float v = sp[rr * SPW + k] + kb[k];
      vals[i] = v;
      mx = fmaxf(mx, v);
    }
#pragma unroll
    for (int off = 4; off; off >>= 1) mx = fmaxf(mx, __shfl_xor(mx, off, 8));
    float s = 0.f;
#pragma unroll
    for (int i = 0; i < 32; i++) {
      float e = __expf(vals[i] - mx);
      s += e;
      spb[rr * SPBW + cg + 8 * i] = f2bf(e);
    }
#pragma unroll
    for (int off = 4; off; off >>= 1) s += __shfl_xor(s, off, 8);
    if (cg == 0) inv[rr] = 1.f / s;
  }
  __syncthreads();

  // ---- PV: O[32][768], wave owns 192 d-columns ----
  f32x4 oacc[2][12];
#pragma unroll
  for (int mt = 0; mt < 2; mt++)
#pragma unroll
    for (int nt = 0; nt < 12; nt++) oacc[mt][nt] = (f32x4)0.f;

  for (int ks = 0; ks < 8; ks++) {
    bf16x8 pa0 = *(const bf16x8*)(&spb[(0 * 16 + m16) * SPBW + ks * 32 + quad * 8]);
    bf16x8 pa1 = *(const bf16x8*)(&spb[(1 * 16 + m16) * SPBW + ks * 32 + quad * 8]);
#pragma unroll
    for (int nt = 0; nt < 12; nt++) {
      const int d = w * 192 + nt * 16 + m16;
      bf16x8 vf = *(const bf16x8*)(vg + (size_t)d * 256 + ks * 32 + quad * 8);
      oacc[0][nt] = __builtin_amdgcn_mfma_f32_16x16x32_bf16(pa0, vf, oacc[0][nt], 0, 0, 0);
      oacc[1][nt] = __builtin_amdgcn_mfma_f32_16x16x32_bf16(pa1, vf, oacc[1][nt], 0, 0, 0);
    }
  }
#pragma unroll
  for (int mt = 0; mt < 2; mt++)
#pragma unroll
    for (int rr = 0; rr < 4; rr++) {
      const int row = mt * 16 + quad * 4 + rr;
      const float iv = inv[row];
      const size_t base = ((size_t)(b * NQ + n0 + row)) * 6144 + (size_t)h * 768;
#pragma unroll
      for (int nt = 0; nt < 12; nt++) {
        const int d = w * 192 + nt * 16 + m16;
        ctx[base + d] = f2bf(oacc[mt][nt][rr] * iv);
      }
    }
}

// ---------------------------------------------------------------------------
// output projection + residual: block = 16 rows, 256 threads,
// thread = (row r=t>>4, component j=t&15); Wo staged per 48-o chunk in LDS.
// OUTPUT fp32.
// ---------------------------------------------------------------------------
__global__ __launch_bounds__(256) void out_kernel(
    const u16* __restrict__ ctx, const float* __restrict__ Wo,
    const float* __restrict__ bo, const float* __restrict__ hidden,
    float* __restrict__ out) {
  const int row0 = blockIdx.x * 16;
  const int t = threadIdx.x;
  const int r = t >> 4, j = t & 15;
  const size_t rowg = (size_t)row0 + r;
  __shared__ __align__(16) float ws[5 * 48 * 48];  // 46 KB: [g][i_out][oc]
  const int gj = grade_of(j);
  float acc[48];
#pragma unroll
  for (int i = 0; i < 48; i++) acc[i] = 0.f;

  for (int ch = 0; ch < 8; ch++) {
    const int o0 = ch * 48;
    __syncthreads();
    for (int idx = t; idx < 5 * 48 * 48; idx += 256) {
      int g = idx / 2304;
      int rem = idx - g * 2304;
      int i = rem / 48, oc = rem - i * 48;
      ws[idx] = Wo[(size_t)(g * 48 + i) * 384 + o0 + oc];
    }
    __syncthreads();
    float xv[48];
#pragma unroll
    for (int oc = 0; oc < 48; oc++)
      xv[oc] = bf2f(ctx[rowg * 6144 + (size_t)(o0 + oc) * 16 + j]);
#pragma unroll 2
    for (int i = 0; i < 48; i++) {
      const float* wr = &ws[(gj * 48 + i) * 48];
      float a = 0.f;
#pragma unroll
      for (int oc = 0; oc < 48; oc += 4) {
        float4 wv = *(const float4*)(wr + oc);
        a += xv[oc] * wv.x + xv[oc + 1] * wv.y + xv[oc + 2] * wv.z + xv[oc + 3] * wv.w;
      }
      acc[i] += a;
    }
  }
#pragma unroll
  for (int i = 0; i < 48; i++) {
    size_t oi = rowg * 768 + (size_t)i * 16 + j;
    float bias = (j == 0) ? bo[i] : 0.f;
    out[oi] = acc[i] + bias + hidden[oi];
  }
}

// ---------------------------------------------------------------------------
extern "C" void kernel_launch(void* const* d_in, const int* in_sizes, int n_in,
                              void* d_out, int out_size, void* d_ws, size_t ws_size,
                              hipStream_t stream) {
  const float* hidden = (const float*)d_in[0];
  const float* vis = (const float*)d_in[1];
  const float* lnw = (const float*)d_in[2];
  const float* Wq = (const float*)d_in[3];
  const float* bq = (const float*)d_in[4];
  const float* Wkv = (const float*)d_in[5];
  const float* bkv = (const float*)d_in[6];
  const float* Wo = (const float*)d_in[7];
  const float* bo = (const float*)d_in[8];
  const float* daa = (const float*)d_in[9];
  float* out = (float*)d_out;

  char* ws = (char*)d_ws;
  size_t off = 0;
  auto carve = [&](size_t bytes) -> void* {
    void* p = ws + off;
    off += (bytes + 255) & ~(size_t)255;
    return p;
  };
  u16* qsel = (u16*)carve((size_t)BB * HH * NQ * KD * 2);    // 71.3 MB
  u16* ksel = (u16*)carve((size_t)BB * HH * NK * KD * 2);    // 17.8 MB
  u16* vT = (u16*)carve((size_t)BB * HH * 768 * 256 * 2);    // 25.2 MB
  float* kbias = (float*)carve((size_t)BB * HH * NK * 4);    // 64 KB
  u16* ctx = (u16*)carve((size_t)BB * NQ * 6144 * 2);        // 100.7 MB

  kv_kernel<<<BB * NK / 16, 256, 0, stream>>>(vis, Wkv, bkv, daa, ksel, kbias, vT);
  q_kernel<<<BB * NQ / 16, 256, 0, stream>>>(hidden, lnw, Wq, bq, daa, qsel);
  attn_kernel<<<dim3(NQ / 32, HH, BB), 256, 0, stream>>>(qsel, ksel, kbias, vT, ctx);
  out_kernel<<<BB * NQ / 16, 256, 0, stream>>>(ctx, Wo, bo, hidden, out);
}

// Round 5
// 1111.859 us; speedup vs baseline: 2.5858x; 1.3518x over previous
//
#include <hip/hip_runtime.h>

typedef unsigned short u16;
typedef unsigned int u32;
typedef unsigned long long u64;

typedef float f32x4 __attribute__((ext_vector_type(4)));
typedef short bf16x8 __attribute__((ext_vector_type(8)));

#define BB 8
#define NQ 1024
#define NK 256
#define HH 8
#define KD 544   // padded score-dot length (11*48=528 -> 544 = 17*32)

__device__ __forceinline__ float bf2f(u16 u) {
  union { u32 i; float f; } v; v.i = ((u32)u) << 16; return v.f;
}
__device__ __forceinline__ u16 f2bf(float f) {
  union { u32 i; float f; } v; v.f = f;
  u32 i = v.i;
  return (u16)((i + 0x7FFFu + ((i >> 16) & 1u)) >> 16);
}
__device__ __forceinline__ float softplusf(float d) {
  return (d > 20.f) ? d : log1pf(__expf(d));
}

// grade per component c (GRADE_IDX), nibble-packed
#define GRADE_TAB 0x4333322222211110ULL
// active component for score-slot s (slots 0..10 = INNER(8) then POINT(3))
#define ACT_TAB   0xDCBEA984320ULL
__device__ __forceinline__ int grade_of(int c) { return (int)((GRADE_TAB >> (c * 4)) & 15ULL); }
__device__ __forceinline__ int act_of(int s) { return (int)((ACT_TAB >> (s * 4)) & 15ULL); }

constexpr float INV_S384 = 0.05103103630798288f; // 1/sqrt(8*48)

// ---------------------------------------------------------------------------
// rms_kernel: rscale[row] = rsqrt(mean_i sum_c x^2 /48 + eps). 32 rows/block.
// ---------------------------------------------------------------------------
__global__ __launch_bounds__(256) void rms_kernel(const float* __restrict__ hidden,
                                                  float* __restrict__ rscale) {
  const int t = threadIdx.x;
  const int row = blockIdx.x * 32 + (t >> 3);
  const int l = t & 7;
  const float4* src = (const float4*)(hidden + (size_t)row * 768);
  float s = 0.f;
#pragma unroll
  for (int k = 0; k < 24; k++) {
    float4 v = src[l + 8 * k];
    s += v.x * v.x + v.y * v.y + v.z * v.z + v.w * v.w;
  }
#pragma unroll
  for (int off = 4; off; off >>= 1) s += __shfl_xor(s, off, 8);
  if (l == 0) rscale[row] = rsqrtf(s * (1.f / 48.f) + 1e-6f);
}

// ---------------------------------------------------------------------------
// wT_kernel: WqT[g][i][o] = Wq[g][o][i]; WkvT[g][i][o] = Wkv[g][o][i].
// ---------------------------------------------------------------------------
__global__ __launch_bounds__(256) void wT_kernel(const float* __restrict__ Wq,
                                                 const float* __restrict__ Wkv,
                                                 float* __restrict__ WqT,
                                                 float* __restrict__ WkvT) {
  int idx = blockIdx.x * 256 + threadIdx.x;
  const int NQT = 5 * 48 * 384;
  if (idx < NQT) {
    int g = idx / 18432;
    int rem = idx - g * 18432;
    int i = rem / 384, o = rem - i * 384;
    WqT[idx] = Wq[((size_t)g * 384 + o) * 48 + i];
  } else if (idx < NQT + 5 * 48 * 768) {
    int j = idx - NQT;
    int g = j / 36864;
    int rem = j - g * 36864;
    int i = rem / 768, o = rem - i * 768;
    WkvT[j] = Wkv[((size_t)g * 768 + o) * 48 + i];
  }
}

// ---------------------------------------------------------------------------
// q_kernel: wave = one active component c (11 of 12 waves across grid.y=3),
// lane = row.  Weights via scalar loads from WqT.  grid = (128, 3, 2).
// ---------------------------------------------------------------------------
__global__ __launch_bounds__(256) void q_kernel(
    const float* __restrict__ hidden, const float* __restrict__ lnw,
    const float* __restrict__ WqT, const float* __restrict__ bq,
    const float* __restrict__ daa, const float* __restrict__ rscale,
    u16* __restrict__ qsel) {
  const int wid = __builtin_amdgcn_readfirstlane(threadIdx.x >> 6);
  const int task = blockIdx.y * 4 + wid;  // 0..11
  const int lane = threadIdx.x & 63;
  const int row = blockIdx.x * 64 + lane; // 0..8191
  const int b = row >> 10, n = row & 1023;
  const int o0 = blockIdx.z * 192;

  if (blockIdx.y == 0 && blockIdx.z == 0) {
    // zero the KD pad [528,544) for this block's 64 rows, all h
    const int row0 = blockIdx.x * 64;
    const int bb = row0 >> 10, n0 = row0 & 1023;
    uint4 z4 = {0u, 0u, 0u, 0u};
    for (int m = threadIdx.x; m < 1024; m += 256) {
      int h = m >> 7, r = (m >> 1) & 63, half = m & 1;
      *(uint4*)(qsel + ((size_t)(bb * HH + h) * NQ + n0 + r) * KD + 528 + half * 8) = z4;
    }
  }
  if (task >= 11) return;

  const int c = act_of(task);
  const int slot = task;
  const int g = grade_of(c);
  const float rs = rscale[row];
  float xr[48];
#pragma unroll
  for (int i = 0; i < 48; i++)
    xr[i] = hidden[(size_t)row * 768 + i * 16 + c] * rs * lnw[i];
  const bool isc0 = (c == 0);

  for (int og = 0; og < 24; og++) {
    const int o = o0 + og * 8;   // 8 outputs, same h (48%8==0)
    const int h = o / 48;
    const int oc = o - h * 48;
    float acc[8];
#pragma unroll
    for (int k = 0; k < 8; k++) acc[k] = 0.f;
#pragma unroll 4
    for (int i = 0; i < 48; i++) {
      const float* wr = WqT + ((size_t)(g * 48 + i)) * 384 + o;  // wave-uniform
      const float xv = xr[i];
#pragma unroll
      for (int k = 0; k < 8; k++) acc[k] += xv * wr[k];
    }
    if (isc0) {
#pragma unroll
      for (int k = 0; k < 8; k++) acc[k] += bq[o + k];
    }
    const float sc = (slot < 8) ? INV_S384 : (2.f * softplusf(daa[h]) * (1.f / 48.f));
    u32 p0 = (u32)f2bf(acc[0] * sc) | ((u32)f2bf(acc[1] * sc) << 16);
    u32 p1 = (u32)f2bf(acc[2] * sc) | ((u32)f2bf(acc[3] * sc) << 16);
    u32 p2 = (u32)f2bf(acc[4] * sc) | ((u32)f2bf(acc[5] * sc) << 16);
    u32 p3 = (u32)f2bf(acc[6] * sc) | ((u32)f2bf(acc[7] * sc) << 16);
    uint4 pk = {p0, p1, p2, p3};
    *(uint4*)(qsel + ((size_t)(b * HH + h) * NQ + n) * KD + slot * 48 + oc) = pk;
  }
}

// ---------------------------------------------------------------------------
// kv_kernel: tasks 0..10 = k components (packed ksel + k2), 11..26 = v
// components (vT, coalesced), 27 idle.  grid = (32, 7, 2).
// ---------------------------------------------------------------------------
__global__ __launch_bounds__(256) void kv_kernel(
    const float* __restrict__ vis, const float* __restrict__ WkvT,
    const float* __restrict__ bkv, const float* __restrict__ daa,
    u16* __restrict__ ksel, float* __restrict__ kbias, u16* __restrict__ vT) {
  __shared__ float k2s[64 * 8];
  const int wid = __builtin_amdgcn_readfirstlane(threadIdx.x >> 6);
  const int task = blockIdx.y * 4 + wid;  // 0..27
  const int lane = threadIdx.x & 63;
  const int row = blockIdx.x * 64 + lane; // 0..2047
  const int b = row >> 8, n = row & 255;
  const int o0 = blockIdx.z * 192;

  k2s[threadIdx.x] = 0.f;
  k2s[threadIdx.x + 256] = 0.f;
  __syncthreads();

  if (blockIdx.y == 0 && blockIdx.z == 0) {
    const int row0 = blockIdx.x * 64;
    const int bb = row0 >> 8, n0 = row0 & 255;
    uint4 z4 = {0u, 0u, 0u, 0u};
    for (int m = threadIdx.x; m < 1024; m += 256) {
      int h = m >> 7, r = (m >> 1) & 63, half = m & 1;
      *(uint4*)(ksel + ((size_t)(bb * HH + h) * NK + n0 + r) * KD + 528 + half * 8) = z4;
    }
  }

  if (task < 11) {  // k component
    const int c = act_of(task);
    const int slot = task;
    const int g = grade_of(c);
    float xr[48];
#pragma unroll
    for (int i = 0; i < 48; i++) xr[i] = vis[(size_t)row * 768 + i * 16 + c];
    const bool isc0 = (c == 0);
    const bool ispt = (task >= 8);  // c in {11,12,13}
    for (int og = 0; og < 24; og++) {
      const int o = o0 + og * 8;
      const int h = o / 48, oc = o - h * 48;
      float acc[8];
#pragma unroll
      for (int k = 0; k < 8; k++) acc[k] = 0.f;
#pragma unroll 4
      for (int i = 0; i < 48; i++) {
        const float* wr = WkvT + ((size_t)(g * 48 + i)) * 768 + o;
        const float xv = xr[i];
#pragma unroll
        for (int k = 0; k < 8; k++) acc[k] += xv * wr[k];
      }
      if (isc0) {
#pragma unroll
        for (int k = 0; k < 8; k++) acc[k] += bkv[o + k];
      }
      u32 p0 = (u32)f2bf(acc[0]) | ((u32)f2bf(acc[1]) << 16);
      u32 p1 = (u32)f2bf(acc[2]) | ((u32)f2bf(acc[3]) << 16);
      u32 p2 = (u32)f2bf(acc[4]) | ((u32)f2bf(acc[5]) << 16);
      u32 p3 = (u32)f2bf(acc[6]) | ((u32)f2bf(acc[7]) << 16);
      uint4 pk = {p0, p1, p2, p3};
      *(uint4*)(ksel + ((size_t)(b * HH + h) * NK + n) * KD + slot * 48 + oc) = pk;
      if (ispt) {
        float s2 = 0.f;
#pragma unroll
        for (int k = 0; k < 8; k++) s2 += acc[k] * acc[k];
        atomicAdd(&k2s[lane * 8 + h], s2);
      }
    }
  } else if (task < 27) {  // v component
    const int c = task - 11;
    const int g = grade_of(c);
    float xr[48];
#pragma unroll
    for (int i = 0; i < 48; i++) xr[i] = vis[(size_t)row * 768 + i * 16 + c];
    const bool isc0 = (c == 0);
    for (int og = 0; og < 24; og++) {
      const int o = o0 + og * 8;  // o2
      const int h = o / 48, oc = o - h * 48;
      float acc[8];
#pragma unroll
      for (int k = 0; k < 8; k++) acc[k] = 0.f;
#pragma unroll 4
      for (int i = 0; i < 48; i++) {
        const float* wr = WkvT + ((size_t)(g * 48 + i)) * 768 + 384 + o;
        const float xv = xr[i];
#pragma unroll
        for (int k = 0; k < 8; k++) acc[k] += xv * wr[k];
      }
      if (isc0) {
#pragma unroll
        for (int k = 0; k < 8; k++) acc[k] += bkv[384 + o + k];
      }
#pragma unroll
      for (int k = 0; k < 8; k++)
        vT[((size_t)(b * HH + h) * 768 + (oc + k) * 16 + c) * 256 + n] = f2bf(acc[k]);
    }
  }
  __syncthreads();
  if (blockIdx.y == 2) {  // block containing the 3 point waves
    const int row0 = blockIdx.x * 64;
    const int bb = row0 >> 8, n0 = row0 & 255;
    int m = threadIdx.x;  // 256 = 64 rows x 4 h
    int rr = m >> 2, h = blockIdx.z * 4 + (m & 3);
    kbias[(size_t)(bb * HH + h) * NK + n0 + rr] =
        -(softplusf(daa[h]) * (1.f / 48.f)) * k2s[rr * 8 + h];
  }
}

// ---------------------------------------------------------------------------
// MFMA attention: unchanged from R4 (verified correct).
// ---------------------------------------------------------------------------
#define SPW 260
#define SPBW 264
__global__ __launch_bounds__(256) void attn_kernel(
    const u16* __restrict__ qsel, const u16* __restrict__ ksel,
    const float* __restrict__ kbias, const u16* __restrict__ vT,
    u16* __restrict__ ctx) {
  const int qt = blockIdx.x, h = blockIdx.y, b = blockIdx.z;
  const int t = threadIdx.x;
  const int w = t >> 6;
  const int lane = t & 63;
  const int m16 = lane & 15;
  const int quad = lane >> 4;

  __shared__ __align__(16) float sp[32 * SPW];
  __shared__ __align__(16) u16 spb[32 * SPBW];
  __shared__ float kb[256];
  __shared__ float inv[32];

  const size_t bh = (size_t)(b * HH + h);
  const int n0 = qt * 32;
  const u16* qg = qsel + (bh * NQ + n0) * KD;
  const u16* kg = ksel + bh * NK * KD;
  const u16* vg = vT + bh * 768 * 256;

  kb[t] = kbias[bh * NK + t];

  f32x4 sacc[2][4];
#pragma unroll
  for (int mt = 0; mt < 2; mt++)
#pragma unroll
    for (int nt = 0; nt < 4; nt++) sacc[mt][nt] = (f32x4)0.f;

  for (int ks = 0; ks < 17; ks++) {
    bf16x8 qa0 = *(const bf16x8*)(qg + (size_t)(0 * 16 + m16) * KD + ks * 32 + quad * 8);
    bf16x8 qa1 = *(const bf16x8*)(qg + (size_t)(1 * 16 + m16) * KD + ks * 32 + quad * 8);
#pragma unroll
    for (int nt = 0; nt < 4; nt++) {
      bf16x8 kf = *(const bf16x8*)(kg + (size_t)(w * 64 + nt * 16 + m16) * KD + ks * 32 + quad * 8);
      sacc[0][nt] = __builtin_amdgcn_mfma_f32_16x16x32_bf16(qa0, kf, sacc[0][nt], 0, 0, 0);
      sacc[1][nt] = __builtin_amdgcn_mfma_f32_16x16x32_bf16(qa1, kf, sacc[1][nt], 0, 0, 0);
    }
  }
#pragma unroll
  for (int mt = 0; mt < 2; mt++)
#pragma unroll
    for (int nt = 0; nt < 4; nt++)
#pragma unroll
      for (int rr = 0; rr < 4; rr++)
        sp[(mt * 16 + quad * 4 + rr) * SPW + w * 64 + nt * 16 + m16] = sacc[mt][nt][rr];
  __syncthreads();

  {
    const int rr = t >> 3, cg = t & 7;
    float vals[32];
    float mx = -1e30f;
#pragma unroll
    for (int i = 0; i < 32; i++) {
      int k = cg + 8 * i;
      float v = sp[rr * SPW + k] + kb[k];
      vals[i] = v;
      mx = fmaxf(mx, v);
    }
#pragma unroll
    for (int off = 4; off; off >>= 1) mx = fmaxf(mx, __shfl_xor(mx, off, 8));
    float s = 0.f;
#pragma unroll
    for (int i = 0; i < 32; i++) {
      float e = __expf(vals[i] - mx);
      s += e;
      spb[rr * SPBW + cg + 8 * i] = f2bf(e);
    }
#pragma unroll
    for (int off = 4; off; off >>= 1) s += __shfl_xor(s, off, 8);
    if (cg == 0) inv[rr] = 1.f / s;
  }
  __syncthreads();

  f32x4 oacc[2][12];
#pragma unroll
  for (int mt = 0; mt < 2; mt++)
#pragma unroll
    for (int nt = 0; nt < 12; nt++) oacc[mt][nt] = (f32x4)0.f;

  for (int ks = 0; ks < 8; ks++) {
    bf16x8 pa0 = *(const bf16x8*)(&spb[(0 * 16 + m16) * SPBW + ks * 32 + quad * 8]);
    bf16x8 pa1 = *(const bf16x8*)(&spb[(1 * 16 + m16) * SPBW + ks * 32 + quad * 8]);
#pragma unroll
    for (int nt = 0; nt < 12; nt++) {
      const int d = w * 192 + nt * 16 + m16;
      bf16x8 vf = *(const bf16x8*)(vg + (size_t)d * 256 + ks * 32 + quad * 8);
      oacc[0][nt] = __builtin_amdgcn_mfma_f32_16x16x32_bf16(pa0, vf, oacc[0][nt], 0, 0, 0);
      oacc[1][nt] = __builtin_amdgcn_mfma_f32_16x16x32_bf16(pa1, vf, oacc[1][nt], 0, 0, 0);
    }
  }
#pragma unroll
  for (int mt = 0; mt < 2; mt++)
#pragma unroll
    for (int rr = 0; rr < 4; rr++) {
      const int rw = mt * 16 + quad * 4 + rr;
      const float iv = inv[rw];
      const size_t base = ((size_t)(b * NQ + n0 + rw)) * 6144 + (size_t)h * 768;
#pragma unroll
      for (int nt = 0; nt < 12; nt++) {
        const int d = w * 192 + nt * 16 + m16;
        ctx[base + d] = f2bf(oacc[mt][nt][rr] * iv);
      }
    }
}

// ---------------------------------------------------------------------------
// out_kernel: 1024 threads = 16 waves (wave = component c, lane = row).
// ctx restaged through padded LDS (coalesced global reads, conflict-free
// component reads); Wo rows via scalar loads.  grid = 128.
// ---------------------------------------------------------------------------
#define OSTR 258
__global__ __launch_bounds__(1024) void out_kernel(
    const u16* __restrict__ ctx, const float* __restrict__ Wo,
    const float* __restrict__ bo, const float* __restrict__ hidden,
    float* __restrict__ out) {
  __shared__ u16 xs[64 * OSTR];
  const int t = threadIdx.x;
  const int c = __builtin_amdgcn_readfirstlane(t >> 6);
  const int lane = t & 63;
  const int row0 = blockIdx.x * 64;
  const int row = row0 + lane;
  const int g = grade_of(c);
  float acc[48];
#pragma unroll
  for (int o = 0; o < 48; o++) acc[o] = 0.f;

  const int srow = t >> 4;  // staging row 0..63
  const int sdw = t & 15;   // staging dword 0..15

  for (int ic = 0; ic < 384; ic += 16) {
    __syncthreads();
    {
      const u32* src = (const u32*)(ctx + (size_t)(row0 + srow) * 6144 + ic * 16);
      u32* dst = (u32*)xs + srow * (OSTR / 2);
#pragma unroll
      for (int k = 0; k < 8; k++) dst[sdw + 16 * k] = src[sdw + 16 * k];
    }
    __syncthreads();
    float xv[16];
#pragma unroll
    for (int ii = 0; ii < 16; ii++) xv[ii] = bf2f(xs[lane * OSTR + ii * 16 + c]);
#pragma unroll 4
    for (int o = 0; o < 48; o++) {
      const float* wr = Wo + ((size_t)g * 48 + o) * 384 + ic;  // wave-uniform
      float a = 0.f;
#pragma unroll
      for (int ii = 0; ii < 16; ii++) a += xv[ii] * wr[ii];
      acc[o] += a;
    }
  }
  const bool isc0 = (c == 0);
#pragma unroll 8
  for (int o = 0; o < 48; o++) {
    size_t oi = (size_t)row * 768 + o * 16 + c;
    out[oi] = acc[o] + (isc0 ? bo[o] : 0.f) + hidden[oi];
  }
}

// ---------------------------------------------------------------------------
extern "C" void kernel_launch(void* const* d_in, const int* in_sizes, int n_in,
                              void* d_out, int out_size, void* d_ws, size_t ws_size,
                              hipStream_t stream) {
  const float* hidden = (const float*)d_in[0];
  const float* vis = (const float*)d_in[1];
  const float* lnw = (const float*)d_in[2];
  const float* Wq = (const float*)d_in[3];
  const float* bq = (const float*)d_in[4];
  const float* Wkv = (const float*)d_in[5];
  const float* bkv = (const float*)d_in[6];
  const float* Wo = (const float*)d_in[7];
  const float* bo = (const float*)d_in[8];
  const float* daa = (const float*)d_in[9];
  float* out = (float*)d_out;

  char* ws = (char*)d_ws;
  size_t off = 0;
  auto carve = [&](size_t bytes) -> void* {
    void* p = ws + off;
    off += (bytes + 255) & ~(size_t)255;
    return p;
  };
  float* rscale = (float*)carve((size_t)BB * NQ * 4);
  float* WqT = (float*)carve((size_t)5 * 48 * 384 * 4);
  float* WkvT = (float*)carve((size_t)5 * 48 * 768 * 4);
  u16* qsel = (u16*)carve((size_t)BB * HH * NQ * KD * 2);
  u16* ksel = (u16*)carve((size_t)BB * HH * NK * KD * 2);
  u16* vT = (u16*)carve((size_t)BB * HH * 768 * 256 * 2);
  float* kbias = (float*)carve((size_t)BB * HH * NK * 4);
  u16* ctx = (u16*)carve((size_t)BB * NQ * 6144 * 2);

  rms_kernel<<<BB * NQ / 32, 256, 0, stream>>>(hidden, rscale);
  wT_kernel<<<1080, 256, 0, stream>>>(Wq, Wkv, WqT, WkvT);
  kv_kernel<<<dim3(BB * NK / 64, 7, 2), 256, 0, stream>>>(vis, WkvT, bkv, daa, ksel, kbias, vT);
  q_kernel<<<dim3(BB * NQ / 64, 3, 2), 256, 0, stream>>>(hidden, lnw, WqT, bq, daa, rscale, qsel);
  attn_kernel<<<dim3(NQ / 32, HH, BB), 256, 0, stream>>>(qsel, ksel, kbias, vT, ctx);
  out_kernel<<<BB * NQ / 64, 1024, 0, stream>>>(ctx, Wo, bo, hidden, out);
}

// Round 6
// 869.239 us; speedup vs baseline: 3.3075x; 1.2791x over previous
//
#include <hip/hip_runtime.h>

typedef unsigned short u16;
typedef unsigned int u32;
typedef unsigned long long u64;

typedef float f32x4 __attribute__((ext_vector_type(4)));
typedef short bf16x8 __attribute__((ext_vector_type(8)));

#define BB 8
#define NQ 1024
#define NK 256
#define HH 8
#define KD 544   // padded score-dot length (11*48=528 -> 544 = 17*32)

__device__ __forceinline__ float bf2f(u16 u) {
  union { u32 i; float f; } v; v.i = ((u32)u) << 16; return v.f;
}
__device__ __forceinline__ u16 f2bf(float f) {
  union { u32 i; float f; } v; v.f = f;
  u32 i = v.i;
  return (u16)((i + 0x7FFFu + ((i >> 16) & 1u)) >> 16);
}
__device__ __forceinline__ float softplusf(float d) {
  return (d > 20.f) ? d : log1pf(__expf(d));
}

// grade per component c (GRADE_IDX), nibble-packed
#define GRADE_TAB 0x4333322222211110ULL
// active component for score-slot s (slots 0..10 = INNER(8) then POINT(3))
#define ACT_TAB   0xDCBEA984320ULL
__device__ __forceinline__ int grade_of(int c) { return (int)((GRADE_TAB >> (c * 4)) & 15ULL); }
__device__ __forceinline__ int act_of(int s) { return (int)((ACT_TAB >> (s * 4)) & 15ULL); }

constexpr float INV_S384 = 0.05103103630798288f; // 1/sqrt(8*48)

// ---------------------------------------------------------------------------
// rms_kernel: rscale[row] = rsqrt(mean_i sum_c x^2 /48 + eps). 32 rows/block.
// ---------------------------------------------------------------------------
__global__ __launch_bounds__(256) void rms_kernel(const float* __restrict__ hidden,
                                                  float* __restrict__ rscale) {
  const int t = threadIdx.x;
  const int row = blockIdx.x * 32 + (t >> 3);
  const int l = t & 7;
  const float4* src = (const float4*)(hidden + (size_t)row * 768);
  float s = 0.f;
#pragma unroll
  for (int k = 0; k < 24; k++) {
    float4 v = src[l + 8 * k];
    s += v.x * v.x + v.y * v.y + v.z * v.z + v.w * v.w;
  }
#pragma unroll
  for (int off = 4; off; off >>= 1) s += __shfl_xor(s, off, 8);
  if (l == 0) rscale[row] = rsqrtf(s * (1.f / 48.f) + 1e-6f);
}

// ---------------------------------------------------------------------------
// wT_kernel: WqT[g][i][o] = Wq[g][o][i]; WkvT[g][i][o] = Wkv[g][o][i].
// ---------------------------------------------------------------------------
__global__ __launch_bounds__(256) void wT_kernel(const float* __restrict__ Wq,
                                                 const float* __restrict__ Wkv,
                                                 float* __restrict__ WqT,
                                                 float* __restrict__ WkvT) {
  int idx = blockIdx.x * 256 + threadIdx.x;
  const int NQT = 5 * 48 * 384;
  if (idx < NQT) {
    int g = idx / 18432;
    int rem = idx - g * 18432;
    int i = rem / 384, o = rem - i * 384;
    WqT[idx] = Wq[((size_t)g * 384 + o) * 48 + i];
  } else if (idx < NQT + 5 * 48 * 768) {
    int j = idx - NQT;
    int g = j / 36864;
    int rem = j - g * 36864;
    int i = rem / 768, o = rem - i * 768;
    WkvT[j] = Wkv[((size_t)g * 768 + o) * 48 + i];
  }
}

// ---------------------------------------------------------------------------
// q_kernel: wave = one active component c (11 of 12 waves across grid.y=3),
// lane = row.  Weights via scalar loads from WqT.  grid = (128, 3, 2).
// ---------------------------------------------------------------------------
__global__ __launch_bounds__(256) void q_kernel(
    const float* __restrict__ hidden, const float* __restrict__ lnw,
    const float* __restrict__ WqT, const float* __restrict__ bq,
    const float* __restrict__ daa, const float* __restrict__ rscale,
    u16* __restrict__ qsel) {
  const int wid = __builtin_amdgcn_readfirstlane(threadIdx.x >> 6);
  const int task = blockIdx.y * 4 + wid;  // 0..11
  const int lane = threadIdx.x & 63;
  const int row = blockIdx.x * 64 + lane; // 0..8191
  const int b = row >> 10, n = row & 1023;
  const int o0 = blockIdx.z * 192;

  if (blockIdx.y == 0 && blockIdx.z == 0) {
    // zero the KD pad [528,544) for this block's 64 rows, all h
    const int row0 = blockIdx.x * 64;
    const int bb = row0 >> 10, n0 = row0 & 1023;
    uint4 z4 = {0u, 0u, 0u, 0u};
    for (int m = threadIdx.x; m < 1024; m += 256) {
      int h = m >> 7, r = (m >> 1) & 63, half = m & 1;
      *(uint4*)(qsel + ((size_t)(bb * HH + h) * NQ + n0 + r) * KD + 528 + half * 8) = z4;
    }
  }
  if (task >= 11) return;

  const int c = act_of(task);
  const int slot = task;
  const int g = grade_of(c);
  const float rs = rscale[row];
  float xr[48];
#pragma unroll
  for (int i = 0; i < 48; i++)
    xr[i] = hidden[(size_t)row * 768 + i * 16 + c] * rs * lnw[i];
  const bool isc0 = (c == 0);

  for (int og = 0; og < 24; og++) {
    const int o = o0 + og * 8;   // 8 outputs, same h (48%8==0)
    const int h = o / 48;
    const int oc = o - h * 48;
    float acc[8];
#pragma unroll
    for (int k = 0; k < 8; k++) acc[k] = 0.f;
#pragma unroll 4
    for (int i = 0; i < 48; i++) {
      const float* wr = WqT + ((size_t)(g * 48 + i)) * 384 + o;  // wave-uniform
      const float xv = xr[i];
#pragma unroll
      for (int k = 0; k < 8; k++) acc[k] += xv * wr[k];
    }
    if (isc0) {
#pragma unroll
      for (int k = 0; k < 8; k++) acc[k] += bq[o + k];
    }
    const float sc = (slot < 8) ? INV_S384 : (2.f * softplusf(daa[h]) * (1.f / 48.f));
    u32 p0 = (u32)f2bf(acc[0] * sc) | ((u32)f2bf(acc[1] * sc) << 16);
    u32 p1 = (u32)f2bf(acc[2] * sc) | ((u32)f2bf(acc[3] * sc) << 16);
    u32 p2 = (u32)f2bf(acc[4] * sc) | ((u32)f2bf(acc[5] * sc) << 16);
    u32 p3 = (u32)f2bf(acc[6] * sc) | ((u32)f2bf(acc[7] * sc) << 16);
    uint4 pk = {p0, p1, p2, p3};
    *(uint4*)(qsel + ((size_t)(b * HH + h) * NQ + n) * KD + slot * 48 + oc) = pk;
  }
}

// ---------------------------------------------------------------------------
// kv_kernel: tasks 0..10 = k components (packed ksel + k2), 11..26 = v
// components (vT, coalesced), 27 idle.  grid = (32, 7, 2).
// ---------------------------------------------------------------------------
__global__ __launch_bounds__(256) void kv_kernel(
    const float* __restrict__ vis, const float* __restrict__ WkvT,
    const float* __restrict__ bkv, const float* __restrict__ daa,
    u16* __restrict__ ksel, float* __restrict__ kbias, u16* __restrict__ vT) {
  __shared__ float k2s[64 * 8];
  const int wid = __builtin_amdgcn_readfirstlane(threadIdx.x >> 6);
  const int task = blockIdx.y * 4 + wid;  // 0..27
  const int lane = threadIdx.x & 63;
  const int row = blockIdx.x * 64 + lane; // 0..2047
  const int b = row >> 8, n = row & 255;
  const int o0 = blockIdx.z * 192;

  k2s[threadIdx.x] = 0.f;
  k2s[threadIdx.x + 256] = 0.f;
  __syncthreads();

  if (blockIdx.y == 0 && blockIdx.z == 0) {
    const int row0 = blockIdx.x * 64;
    const int bb = row0 >> 8, n0 = row0 & 255;
    uint4 z4 = {0u, 0u, 0u, 0u};
    for (int m = threadIdx.x; m < 1024; m += 256) {
      int h = m >> 7, r = (m >> 1) & 63, half = m & 1;
      *(uint4*)(ksel + ((size_t)(bb * HH + h) * NK + n0 + r) * KD + 528 + half * 8) = z4;
    }
  }

  if (task < 11) {  // k component
    const int c = act_of(task);
    const int slot = task;
    const int g = grade_of(c);
    float xr[48];
#pragma unroll
    for (int i = 0; i < 48; i++) xr[i] = vis[(size_t)row * 768 + i * 16 + c];
    const bool isc0 = (c == 0);
    const bool ispt = (task >= 8);  // c in {11,12,13}
    for (int og = 0; og < 24; og++) {
      const int o = o0 + og * 8;
      const int h = o / 48, oc = o - h * 48;
      float acc[8];
#pragma unroll
      for (int k = 0; k < 8; k++) acc[k] = 0.f;
#pragma unroll 4
      for (int i = 0; i < 48; i++) {
        const float* wr = WkvT + ((size_t)(g * 48 + i)) * 768 + o;
        const float xv = xr[i];
#pragma unroll
        for (int k = 0; k < 8; k++) acc[k] += xv * wr[k];
      }
      if (isc0) {
#pragma unroll
        for (int k = 0; k < 8; k++) acc[k] += bkv[o + k];
      }
      u32 p0 = (u32)f2bf(acc[0]) | ((u32)f2bf(acc[1]) << 16);
      u32 p1 = (u32)f2bf(acc[2]) | ((u32)f2bf(acc[3]) << 16);
      u32 p2 = (u32)f2bf(acc[4]) | ((u32)f2bf(acc[5]) << 16);
      u32 p3 = (u32)f2bf(acc[6]) | ((u32)f2bf(acc[7]) << 16);
      uint4 pk = {p0, p1, p2, p3};
      *(uint4*)(ksel + ((size_t)(b * HH + h) * NK + n) * KD + slot * 48 + oc) = pk;
      if (ispt) {
        float s2 = 0.f;
#pragma unroll
        for (int k = 0; k < 8; k++) s2 += acc[k] * acc[k];
        atomicAdd(&k2s[lane * 8 + h], s2);
      }
    }
  } else if (task < 27) {  // v component
    const int c = task - 11;
    const int g = grade_of(c);
    float xr[48];
#pragma unroll
    for (int i = 0; i < 48; i++) xr[i] = vis[(size_t)row * 768 + i * 16 + c];
    const bool isc0 = (c == 0);
    for (int og = 0; og < 24; og++) {
      const int o = o0 + og * 8;  // o2
      const int h = o / 48, oc = o - h * 48;
      float acc[8];
#pragma unroll
      for (int k = 0; k < 8; k++) acc[k] = 0.f;
#pragma unroll 4
      for (int i = 0; i < 48; i++) {
        const float* wr = WkvT + ((size_t)(g * 48 + i)) * 768 + 384 + o;
        const float xv = xr[i];
#pragma unroll
        for (int k = 0; k < 8; k++) acc[k] += xv * wr[k];
      }
      if (isc0) {
#pragma unroll
        for (int k = 0; k < 8; k++) acc[k] += bkv[384 + o + k];
      }
#pragma unroll
      for (int k = 0; k < 8; k++)
        vT[((size_t)(b * HH + h) * 768 + (oc + k) * 16 + c) * 256 + n] = f2bf(acc[k]);
    }
  }
  __syncthreads();
  if (blockIdx.y == 2) {  // block containing the 3 point waves
    const int row0 = blockIdx.x * 64;
    const int bb = row0 >> 8, n0 = row0 & 255;
    int m = threadIdx.x;  // 256 = 64 rows x 4 h
    int rr = m >> 2, h = blockIdx.z * 4 + (m & 3);
    kbias[(size_t)(bb * HH + h) * NK + n0 + rr] =
        -(softplusf(daa[h]) * (1.f / 48.f)) * k2s[rr * 8 + h];
  }
}

// ---------------------------------------------------------------------------
// MFMA attention: unchanged (verified correct).
// ---------------------------------------------------------------------------
#define SPW 260
#define SPBW 264
__global__ __launch_bounds__(256) void attn_kernel(
    const u16* __restrict__ qsel, const u16* __restrict__ ksel,
    const float* __restrict__ kbias, const u16* __restrict__ vT,
    u16* __restrict__ ctx) {
  const int qt = blockIdx.x, h = blockIdx.y, b = blockIdx.z;
  const int t = threadIdx.x;
  const int w = t >> 6;
  const int lane = t & 63;
  const int m16 = lane & 15;
  const int quad = lane >> 4;

  __shared__ __align__(16) float sp[32 * SPW];
  __shared__ __align__(16) u16 spb[32 * SPBW];
  __shared__ float kb[256];
  __shared__ float inv[32];

  const size_t bh = (size_t)(b * HH + h);
  const int n0 = qt * 32;
  const u16* qg = qsel + (bh * NQ + n0) * KD;
  const u16* kg = ksel + bh * NK * KD;
  const u16* vg = vT + bh * 768 * 256;

  kb[t] = kbias[bh * NK + t];

  f32x4 sacc[2][4];
#pragma unroll
  for (int mt = 0; mt < 2; mt++)
#pragma unroll
    for (int nt = 0; nt < 4; nt++) sacc[mt][nt] = (f32x4)0.f;

  for (int ks = 0; ks < 17; ks++) {
    bf16x8 qa0 = *(const bf16x8*)(qg + (size_t)(0 * 16 + m16) * KD + ks * 32 + quad * 8);
    bf16x8 qa1 = *(const bf16x8*)(qg + (size_t)(1 * 16 + m16) * KD + ks * 32 + quad * 8);
#pragma unroll
    for (int nt = 0; nt < 4; nt++) {
      bf16x8 kf = *(const bf16x8*)(kg + (size_t)(w * 64 + nt * 16 + m16) * KD + ks * 32 + quad * 8);
      sacc[0][nt] = __builtin_amdgcn_mfma_f32_16x16x32_bf16(qa0, kf, sacc[0][nt], 0, 0, 0);
      sacc[1][nt] = __builtin_amdgcn_mfma_f32_16x16x32_bf16(qa1, kf, sacc[1][nt], 0, 0, 0);
    }
  }
#pragma unroll
  for (int mt = 0; mt < 2; mt++)
#pragma unroll
    for (int nt = 0; nt < 4; nt++)
#pragma unroll
      for (int rr = 0; rr < 4; rr++)
        sp[(mt * 16 + quad * 4 + rr) * SPW + w * 64 + nt * 16 + m16] = sacc[mt][nt][rr];
  __syncthreads();

  {
    const int rr = t >> 3, cg = t & 7;
    float vals[32];
    float mx = -1e30f;
#pragma unroll
    for (int i = 0; i < 32; i++) {
      int k = cg + 8 * i;
      float v = sp[rr * SPW + k] + kb[k];
      vals[i] = v;
      mx = fmaxf(mx, v);
    }
#pragma unroll
    for (int off = 4; off; off >>= 1) mx = fmaxf(mx, __shfl_xor(mx, off, 8));
    float s = 0.f;
#pragma unroll
    for (int i = 0; i < 32; i++) {
      float e = __expf(vals[i] - mx);
      s += e;
      spb[rr * SPBW + cg + 8 * i] = f2bf(e);
    }
#pragma unroll
    for (int off = 4; off; off >>= 1) s += __shfl_xor(s, off, 8);
    if (cg == 0) inv[rr] = 1.f / s;
  }
  __syncthreads();

  f32x4 oacc[2][12];
#pragma unroll
  for (int mt = 0; mt < 2; mt++)
#pragma unroll
    for (int nt = 0; nt < 12; nt++) oacc[mt][nt] = (f32x4)0.f;

  for (int ks = 0; ks < 8; ks++) {
    bf16x8 pa0 = *(const bf16x8*)(&spb[(0 * 16 + m16) * SPBW + ks * 32 + quad * 8]);
    bf16x8 pa1 = *(const bf16x8*)(&spb[(1 * 16 + m16) * SPBW + ks * 32 + quad * 8]);
#pragma unroll
    for (int nt = 0; nt < 12; nt++) {
      const int d = w * 192 + nt * 16 + m16;
      bf16x8 vf = *(const bf16x8*)(vg + (size_t)d * 256 + ks * 32 + quad * 8);
      oacc[0][nt] = __builtin_amdgcn_mfma_f32_16x16x32_bf16(pa0, vf, oacc[0][nt], 0, 0, 0);
      oacc[1][nt] = __builtin_amdgcn_mfma_f32_16x16x32_bf16(pa1, vf, oacc[1][nt], 0, 0, 0);
    }
  }
#pragma unroll
  for (int mt = 0; mt < 2; mt++)
#pragma unroll
    for (int rr = 0; rr < 4; rr++) {
      const int rw = mt * 16 + quad * 4 + rr;
      const float iv = inv[rw];
      const size_t base = ((size_t)(b * NQ + n0 + rw)) * 6144 + (size_t)h * 768;
#pragma unroll
      for (int nt = 0; nt < 12; nt++) {
        const int d = w * 192 + nt * 16 + m16;
        ctx[base + d] = f2bf(oacc[mt][nt][rr] * iv);
      }
    }
}

// ---------------------------------------------------------------------------
// out_kernel v2: grid (128, 2), block 1024 = 16 waves (wave = component c,
// lane = row; 64 rows/block).  Block y computes o in [y*24, y*24+24).
// Main loop: ctx restaged through LDS (coalesced reads, conflict-free
// component reads); Wo rows via wave-uniform scalar loads.
// Epilogue: acc staged to LDS in 16-row chunks, written to out as contiguous
// float4 full lines with residual (hidden) read coalesced.  OUTPUT fp32.
// ---------------------------------------------------------------------------
#define OSTR 258            // u16 stride for ctx staging rows
#define ESTR 388            // f32 stride for epilogue staging rows (384+4)
__global__ __launch_bounds__(1024) void out_kernel(
    const u16* __restrict__ ctx, const float* __restrict__ Wo,
    const float* __restrict__ bo, const float* __restrict__ hidden,
    float* __restrict__ out) {
  __shared__ __align__(16) char smem[64 * OSTR * 2];  // 33 KB, dual-purpose
  u16* xs = (u16*)smem;
  float* es = (float*)smem;
  const int t = threadIdx.x;
  const int c = __builtin_amdgcn_readfirstlane(t >> 6);
  const int lane = t & 63;
  const int row0 = blockIdx.x * 64;
  const int ob = blockIdx.y * 24;   // this block's first output channel
  const int g = grade_of(c);
  float acc[24];
#pragma unroll
  for (int o = 0; o < 24; o++) acc[o] = 0.f;

  const int srow = t >> 4;  // staging row 0..63
  const int sdw = t & 15;   // staging dword 0..15

  for (int ic = 0; ic < 384; ic += 16) {
    __syncthreads();
    {
      const u32* src = (const u32*)(ctx + (size_t)(row0 + srow) * 6144 + ic * 16);
      u32* dst = (u32*)xs + srow * (OSTR / 2);
#pragma unroll
      for (int k = 0; k < 8; k++) dst[sdw + 16 * k] = src[sdw + 16 * k];
    }
    __syncthreads();
    float xv[16];
#pragma unroll
    for (int ii = 0; ii < 16; ii++) xv[ii] = bf2f(xs[lane * OSTR + ii * 16 + c]);
#pragma unroll 4
    for (int o = 0; o < 24; o++) {
      const float* wr = Wo + ((size_t)g * 48 + ob + o) * 384 + ic;  // wave-uniform
      float a = 0.f;
#pragma unroll
      for (int ii = 0; ii < 16; ii++) a += xv[ii] * wr[ii];
      acc[o] += a;
    }
  }
  if (c == 0) {
#pragma unroll
    for (int o = 0; o < 24; o++) acc[o] += bo[ob + o];
  }

  // epilogue: 4 chunks of 16 rows; stage acc -> LDS, write coalesced + residual
  for (int chunk = 0; chunk < 4; chunk++) {
    __syncthreads();
    if ((lane >> 4) == chunk) {
      const int r16 = lane & 15;
#pragma unroll
      for (int o = 0; o < 24; o++) es[r16 * ESTR + o * 16 + c] = acc[o];
    }
    __syncthreads();
    for (int m = t; m < 1536; m += 1024) {
      int r = m / 96, col = m - r * 96;  // 96 float4 per half-row
      float4 v = *(const float4*)&es[r * ESTR + col * 4];
      size_t gidx = (size_t)(row0 + chunk * 16 + r) * 768 + ob * 16 + col * 4;
      const float4 hv = *(const float4*)&hidden[gidx];
      v.x += hv.x; v.y += hv.y; v.z += hv.z; v.w += hv.w;
      *(float4*)&out[gidx] = v;
    }
  }
}

// ---------------------------------------------------------------------------
extern "C" void kernel_launch(void* const* d_in, const int* in_sizes, int n_in,
                              void* d_out, int out_size, void* d_ws, size_t ws_size,
                              hipStream_t stream) {
  const float* hidden = (const float*)d_in[0];
  const float* vis = (const float*)d_in[1];
  const float* lnw = (const float*)d_in[2];
  const float* Wq = (const float*)d_in[3];
  const float* bq = (const float*)d_in[4];
  const float* Wkv = (const float*)d_in[5];
  const float* bkv = (const float*)d_in[6];
  const float* Wo = (const float*)d_in[7];
  const float* bo = (const float*)d_in[8];
  const float* daa = (const float*)d_in[9];
  float* out = (float*)d_out;

  char* ws = (char*)d_ws;
  size_t off = 0;
  auto carve = [&](size_t bytes) -> void* {
    void* p = ws + off;
    off += (bytes + 255) & ~(size_t)255;
    return p;
  };
  float* rscale = (float*)carve((size_t)BB * NQ * 4);
  float* WqT = (float*)carve((size_t)5 * 48 * 384 * 4);
  float* WkvT = (float*)carve((size_t)5 * 48 * 768 * 4);
  u16* qsel = (u16*)carve((size_t)BB * HH * NQ * KD * 2);
  u16* ksel = (u16*)carve((size_t)BB * HH * NK * KD * 2);
  u16* vT = (u16*)carve((size_t)BB * HH * 768 * 256 * 2);
  float* kbias = (float*)carve((size_t)BB * HH * NK * 4);
  u16* ctx = (u16*)carve((size_t)BB * NQ * 6144 * 2);

  rms_kernel<<<BB * NQ / 32, 256, 0, stream>>>(hidden, rscale);
  wT_kernel<<<1080, 256, 0, stream>>>(Wq, Wkv, WqT, WkvT);
  kv_kernel<<<dim3(BB * NK / 64, 7, 2), 256, 0, stream>>>(vis, WkvT, bkv, daa, ksel, kbias, vT);
  q_kernel<<<dim3(BB * NQ / 64, 3, 2), 256, 0, stream>>>(hidden, lnw, WqT, bq, daa, rscale, qsel);
  attn_kernel<<<dim3(NQ / 32, HH, BB), 256, 0, stream>>>(qsel, ksel, kbias, vT, ctx);
  out_kernel<<<dim3(BB * NQ / 64, 2), 1024, 0, stream>>>(ctx, Wo, bo, hidden, out);
}

// Round 7
// 866.680 us; speedup vs baseline: 3.3173x; 1.0030x over previous
//
#include <hip/hip_runtime.h>

typedef unsigned short u16;
typedef unsigned int u32;
typedef unsigned long long u64;

typedef float f32x4 __attribute__((ext_vector_type(4)));
typedef short bf16x8 __attribute__((ext_vector_type(8)));

#define BB 8
#define NQ 1024
#define NK 256
#define HH 8
#define KD 544   // padded score-dot length (11*48=528 -> 544 = 17*32)

__device__ __forceinline__ float bf2f(u16 u) {
  union { u32 i; float f; } v; v.i = ((u32)u) << 16; return v.f;
}
__device__ __forceinline__ u16 f2bf(float f) {
  union { u32 i; float f; } v; v.f = f;
  u32 i = v.i;
  return (u16)((i + 0x7FFFu + ((i >> 16) & 1u)) >> 16);
}
__device__ __forceinline__ float softplusf(float d) {
  return (d > 20.f) ? d : log1pf(__expf(d));
}

// grade per component c (GRADE_IDX), nibble-packed
#define GRADE_TAB 0x4333322222211110ULL
// active component for score-slot s (slots 0..10 = INNER(8) then POINT(3))
#define ACT_TAB   0xDCBEA984320ULL
__device__ __forceinline__ int grade_of(int c) { return (int)((GRADE_TAB >> (c * 4)) & 15ULL); }
__device__ __forceinline__ int act_of(int s) { return (int)((ACT_TAB >> (s * 4)) & 15ULL); }

constexpr float INV_S384 = 0.05103103630798288f; // 1/sqrt(8*48)

// ---------------------------------------------------------------------------
// rms_kernel: rscale[row] = rsqrt(mean_i sum_c x^2 /48 + eps). 32 rows/block.
// ---------------------------------------------------------------------------
__global__ __launch_bounds__(256) void rms_kernel(const float* __restrict__ hidden,
                                                  float* __restrict__ rscale) {
  const int t = threadIdx.x;
  const int row = blockIdx.x * 32 + (t >> 3);
  const int l = t & 7;
  const float4* src = (const float4*)(hidden + (size_t)row * 768);
  float s = 0.f;
#pragma unroll
  for (int k = 0; k < 24; k++) {
    float4 v = src[l + 8 * k];
    s += v.x * v.x + v.y * v.y + v.z * v.z + v.w * v.w;
  }
#pragma unroll
  for (int off = 4; off; off >>= 1) s += __shfl_xor(s, off, 8);
  if (l == 0) rscale[row] = rsqrtf(s * (1.f / 48.f) + 1e-6f);
}

// ---------------------------------------------------------------------------
// wT_kernel: WqT[g][i][o] = Wq[g][o][i]; WkvT[g][i][o] = Wkv[g][o][i].
// ---------------------------------------------------------------------------
__global__ __launch_bounds__(256) void wT_kernel(const float* __restrict__ Wq,
                                                 const float* __restrict__ Wkv,
                                                 float* __restrict__ WqT,
                                                 float* __restrict__ WkvT) {
  int idx = blockIdx.x * 256 + threadIdx.x;
  const int NQT = 5 * 48 * 384;
  if (idx < NQT) {
    int g = idx / 18432;
    int rem = idx - g * 18432;
    int i = rem / 384, o = rem - i * 384;
    WqT[idx] = Wq[((size_t)g * 384 + o) * 48 + i];
  } else if (idx < NQT + 5 * 48 * 768) {
    int j = idx - NQT;
    int g = j / 36864;
    int rem = j - g * 36864;
    int i = rem / 768, o = rem - i * 768;
    WkvT[j] = Wkv[((size_t)g * 768 + o) * 48 + i];
  }
}

// ---------------------------------------------------------------------------
// xT_kernel: x[row][i*16+c] -> xT[c][i][row] (f32), optional RMS*lnw fold.
// block = 64 rows, LDS-tiled (6 chunks of 128 cols). grid = NR/64.
// ---------------------------------------------------------------------------
__global__ __launch_bounds__(256) void xT_kernel(
    const float* __restrict__ src, float* __restrict__ dst,
    const float* __restrict__ rscale, const float* __restrict__ lnw,
    int NR, int norm) {
  __shared__ __align__(16) float ls[64 * 132];
  __shared__ float rs_s[64];
  const int t = threadIdx.x;
  const int row0 = blockIdx.x * 64;
  if (norm && t < 64) rs_s[t] = rscale[row0 + t];

  const int p = t >> 1, h2 = t & 1;
  const int c = p & 15, il = p >> 4;

  for (int ib = 0; ib < 6; ib++) {
    __syncthreads();
#pragma unroll
    for (int k = 0; k < 8; k++) {
      int idx = t + 256 * k;
      int r = idx >> 5, c4 = idx & 31;
      float4 v = *(const float4*)(src + (size_t)(row0 + r) * 768 + ib * 128 + c4 * 4);
      *(float4*)&ls[r * 132 + c4 * 4] = v;
    }
    __syncthreads();
    const int ig = ib * 8 + il;
    const float lw = norm ? lnw[ig] : 1.f;
    float vbuf[32];
#pragma unroll
    for (int j = 0; j < 32; j++) {
      float v = ls[(h2 * 32 + j) * 132 + il * 16 + c];
      if (norm) v *= rs_s[h2 * 32 + j] * lw;
      vbuf[j] = v;
    }
    float* dp = dst + ((size_t)c * 48 + ig) * NR + row0 + h2 * 32;
#pragma unroll
    for (int j4 = 0; j4 < 8; j4++) {
      float4 v4 = {vbuf[j4 * 4], vbuf[j4 * 4 + 1], vbuf[j4 * 4 + 2], vbuf[j4 * 4 + 3]};
      *(float4*)(dp + j4 * 4) = v4;
    }
  }
}

// ---------------------------------------------------------------------------
// q_kernel: wave = one active component c, lane = row; x from hTn (coalesced),
// weights via wave-uniform scalar loads.  grid = (128, 3, 2).
// ---------------------------------------------------------------------------
__global__ __launch_bounds__(256) void q_kernel(
    const float* __restrict__ hTn, const float* __restrict__ WqT,
    const float* __restrict__ bq, const float* __restrict__ daa,
    u16* __restrict__ qsel) {
  const int wid = __builtin_amdgcn_readfirstlane(threadIdx.x >> 6);
  const int task = blockIdx.y * 4 + wid;  // 0..11
  const int lane = threadIdx.x & 63;
  const int row = blockIdx.x * 64 + lane; // 0..8191
  const int b = row >> 10, n = row & 1023;
  const int o0 = blockIdx.z * 192;

  if (blockIdx.y == 0 && blockIdx.z == 0) {
    const int row0 = blockIdx.x * 64;
    const int bb = row0 >> 10, n0 = row0 & 1023;
    uint4 z4 = {0u, 0u, 0u, 0u};
    for (int m = threadIdx.x; m < 1024; m += 256) {
      int h = m >> 7, r = (m >> 1) & 63, half = m & 1;
      *(uint4*)(qsel + ((size_t)(bb * HH + h) * NQ + n0 + r) * KD + 528 + half * 8) = z4;
    }
  }
  if (task >= 11) return;

  const int c = act_of(task);
  const int slot = task;
  const int g = grade_of(c);
  float xr[48];
  const float* xsrc = hTn + (size_t)c * 48 * 8192 + row;
#pragma unroll
  for (int i = 0; i < 48; i++) xr[i] = xsrc[(size_t)i * 8192];
  const bool isc0 = (c == 0);

  for (int og = 0; og < 24; og++) {
    const int o = o0 + og * 8;   // 8 outputs, same h (48%8==0)
    const int h = o / 48;
    const int oc = o - h * 48;
    float acc[8];
#pragma unroll
    for (int k = 0; k < 8; k++) acc[k] = 0.f;
#pragma unroll 4
    for (int i = 0; i < 48; i++) {
      const float* wr = WqT + ((size_t)(g * 48 + i)) * 384 + o;  // wave-uniform
      const float xv = xr[i];
#pragma unroll
      for (int k = 0; k < 8; k++) acc[k] += xv * wr[k];
    }
    if (isc0) {
#pragma unroll
      for (int k = 0; k < 8; k++) acc[k] += bq[o + k];
    }
    const float sc = (slot < 8) ? INV_S384 : (2.f * softplusf(daa[h]) * (1.f / 48.f));
    u32 p0 = (u32)f2bf(acc[0] * sc) | ((u32)f2bf(acc[1] * sc) << 16);
    u32 p1 = (u32)f2bf(acc[2] * sc) | ((u32)f2bf(acc[3] * sc) << 16);
    u32 p2 = (u32)f2bf(acc[4] * sc) | ((u32)f2bf(acc[5] * sc) << 16);
    u32 p3 = (u32)f2bf(acc[6] * sc) | ((u32)f2bf(acc[7] * sc) << 16);
    uint4 pk = {p0, p1, p2, p3};
    *(uint4*)(qsel + ((size_t)(b * HH + h) * NQ + n) * KD + slot * 48 + oc) = pk;
  }
}

// ---------------------------------------------------------------------------
// kv_kernel: tasks 0..10 = k components, 11..26 = v components; x from visT
// (coalesced).  grid = (32, 7, 2).
// ---------------------------------------------------------------------------
__global__ __launch_bounds__(256) void kv_kernel(
    const float* __restrict__ visT, const float* __restrict__ WkvT,
    const float* __restrict__ bkv, const float* __restrict__ daa,
    u16* __restrict__ ksel, float* __restrict__ kbias, u16* __restrict__ vT) {
  __shared__ float k2s[64 * 8];
  const int wid = __builtin_amdgcn_readfirstlane(threadIdx.x >> 6);
  const int task = blockIdx.y * 4 + wid;  // 0..27
  const int lane = threadIdx.x & 63;
  const int row = blockIdx.x * 64 + lane; // 0..2047
  const int b = row >> 8, n = row & 255;
  const int o0 = blockIdx.z * 192;

  k2s[threadIdx.x] = 0.f;
  k2s[threadIdx.x + 256] = 0.f;
  __syncthreads();

  if (blockIdx.y == 0 && blockIdx.z == 0) {
    const int row0 = blockIdx.x * 64;
    const int bb = row0 >> 8, n0 = row0 & 255;
    uint4 z4 = {0u, 0u, 0u, 0u};
    for (int m = threadIdx.x; m < 1024; m += 256) {
      int h = m >> 7, r = (m >> 1) & 63, half = m & 1;
      *(uint4*)(ksel + ((size_t)(bb * HH + h) * NK + n0 + r) * KD + 528 + half * 8) = z4;
    }
  }

  if (task < 11) {  // k component
    const int c = act_of(task);
    const int slot = task;
    const int g = grade_of(c);
    float xr[48];
    const float* xsrc = visT + (size_t)c * 48 * 2048 + row;
#pragma unroll
    for (int i = 0; i < 48; i++) xr[i] = xsrc[(size_t)i * 2048];
    const bool isc0 = (c == 0);
    const bool ispt = (task >= 8);  // c in {11,12,13}
    for (int og = 0; og < 24; og++) {
      const int o = o0 + og * 8;
      const int h = o / 48, oc = o - h * 48;
      float acc[8];
#pragma unroll
      for (int k = 0; k < 8; k++) acc[k] = 0.f;
#pragma unroll 4
      for (int i = 0; i < 48; i++) {
        const float* wr = WkvT + ((size_t)(g * 48 + i)) * 768 + o;
        const float xv = xr[i];
#pragma unroll
        for (int k = 0; k < 8; k++) acc[k] += xv * wr[k];
      }
      if (isc0) {
#pragma unroll
        for (int k = 0; k < 8; k++) acc[k] += bkv[o + k];
      }
      u32 p0 = (u32)f2bf(acc[0]) | ((u32)f2bf(acc[1]) << 16);
      u32 p1 = (u32)f2bf(acc[2]) | ((u32)f2bf(acc[3]) << 16);
      u32 p2 = (u32)f2bf(acc[4]) | ((u32)f2bf(acc[5]) << 16);
      u32 p3 = (u32)f2bf(acc[6]) | ((u32)f2bf(acc[7]) << 16);
      uint4 pk = {p0, p1, p2, p3};
      *(uint4*)(ksel + ((size_t)(b * HH + h) * NK + n) * KD + slot * 48 + oc) = pk;
      if (ispt) {
        float s2 = 0.f;
#pragma unroll
        for (int k = 0; k < 8; k++) s2 += acc[k] * acc[k];
        atomicAdd(&k2s[lane * 8 + h], s2);
      }
    }
  } else if (task < 27) {  // v component
    const int c = task - 11;
    const int g = grade_of(c);
    float xr[48];
    const float* xsrc = visT + (size_t)c * 48 * 2048 + row;
#pragma unroll
    for (int i = 0; i < 48; i++) xr[i] = xsrc[(size_t)i * 2048];
    const bool isc0 = (c == 0);
    for (int og = 0; og < 24; og++) {
      const int o = o0 + og * 8;  // o2
      const int h = o / 48, oc = o - h * 48;
      float acc[8];
#pragma unroll
      for (int k = 0; k < 8; k++) acc[k] = 0.f;
#pragma unroll 4
      for (int i = 0; i < 48; i++) {
        const float* wr = WkvT + ((size_t)(g * 48 + i)) * 768 + 384 + o;
        const float xv = xr[i];
#pragma unroll
        for (int k = 0; k < 8; k++) acc[k] += xv * wr[k];
      }
      if (isc0) {
#pragma unroll
        for (int k = 0; k < 8; k++) acc[k] += bkv[384 + o + k];
      }
#pragma unroll
      for (int k = 0; k < 8; k++)
        vT[((size_t)(b * HH + h) * 768 + (oc + k) * 16 + c) * 256 + n] = f2bf(acc[k]);
    }
  }
  __syncthreads();
  if (blockIdx.y == 2) {
    const int row0 = blockIdx.x * 64;
    const int bb = row0 >> 8, n0 = row0 & 255;
    int m = threadIdx.x;  // 256 = 64 rows x 4 h
    int rr = m >> 2, h = blockIdx.z * 4 + (m & 3);
    kbias[(size_t)(bb * HH + h) * NK + n0 + rr] =
        -(softplusf(daa[h]) * (1.f / 48.f)) * k2s[rr * 8 + h];
  }
}

// ---------------------------------------------------------------------------
// MFMA attention.  Scores unchanged.  PV computes O^T via operand swap
// (A = vT d-frags, B = P row-frags) so the store is component-major:
// ctxT[c][i=h*48+oc][row_global], 32B-contiguous chunks.
// ---------------------------------------------------------------------------
#define SPW 260
#define SPBW 264
__global__ __launch_bounds__(256) void attn_kernel(
    const u16* __restrict__ qsel, const u16* __restrict__ ksel,
    const float* __restrict__ kbias, const u16* __restrict__ vT,
    u16* __restrict__ ctxT) {
  const int qt = blockIdx.x, h = blockIdx.y, b = blockIdx.z;
  const int t = threadIdx.x;
  const int w = t >> 6;
  const int lane = t & 63;
  const int m16 = lane & 15;
  const int quad = lane >> 4;

  __shared__ __align__(16) float sp[32 * SPW];
  __shared__ __align__(16) u16 spb[32 * SPBW];
  __shared__ float kb[256];
  __shared__ float inv[32];

  const size_t bh = (size_t)(b * HH + h);
  const int n0 = qt * 32;
  const u16* qg = qsel + (bh * NQ + n0) * KD;
  const u16* kg = ksel + bh * NK * KD;
  const u16* vg = vT + bh * 768 * 256;

  kb[t] = kbias[bh * NK + t];

  f32x4 sacc[2][4];
#pragma unroll
  for (int mt = 0; mt < 2; mt++)
#pragma unroll
    for (int nt = 0; nt < 4; nt++) sacc[mt][nt] = (f32x4)0.f;

  for (int ks = 0; ks < 17; ks++) {
    bf16x8 qa0 = *(const bf16x8*)(qg + (size_t)(0 * 16 + m16) * KD + ks * 32 + quad * 8);
    bf16x8 qa1 = *(const bf16x8*)(qg + (size_t)(1 * 16 + m16) * KD + ks * 32 + quad * 8);
#pragma unroll
    for (int nt = 0; nt < 4; nt++) {
      bf16x8 kf = *(const bf16x8*)(kg + (size_t)(w * 64 + nt * 16 + m16) * KD + ks * 32 + quad * 8);
      sacc[0][nt] = __builtin_amdgcn_mfma_f32_16x16x32_bf16(qa0, kf, sacc[0][nt], 0, 0, 0);
      sacc[1][nt] = __builtin_amdgcn_mfma_f32_16x16x32_bf16(qa1, kf, sacc[1][nt], 0, 0, 0);
    }
  }
#pragma unroll
  for (int mt = 0; mt < 2; mt++)
#pragma unroll
    for (int nt = 0; nt < 4; nt++)
#pragma unroll
      for (int rr = 0; rr < 4; rr++)
        sp[(mt * 16 + quad * 4 + rr) * SPW + w * 64 + nt * 16 + m16] = sacc[mt][nt][rr];
  __syncthreads();

  {
    const int rr = t >> 3, cg = t & 7;
    float vals[32];
    float mx = -1e30f;
#pragma unroll
    for (int i = 0; i < 32; i++) {
      int k = cg + 8 * i;
      float v = sp[rr * SPW + k] + kb[k];
      vals[i] = v;
      mx = fmaxf(mx, v);
    }
#pragma unroll
    for (int off = 4; off; off >>= 1) mx = fmaxf(mx, __shfl_xor(mx, off, 8));
    float s = 0.f;
#pragma unroll
    for (int i = 0; i < 32; i++) {
      float e = __expf(vals[i] - mx);
      s += e;
      spb[rr * SPBW + cg + 8 * i] = f2bf(e);
    }
#pragma unroll
    for (int off = 4; off; off >>= 1) s += __shfl_xor(s, off, 8);
    if (cg == 0) inv[rr] = 1.f / s;
  }
  __syncthreads();

  // ---- PV (transposed): D[m=d][n=row] = V^T . P^T ----
  f32x4 oaccT[12][2];
#pragma unroll
  for (int nt = 0; nt < 12; nt++)
#pragma unroll
    for (int mt = 0; mt < 2; mt++) oaccT[nt][mt] = (f32x4)0.f;

  for (int ks = 0; ks < 8; ks++) {
    bf16x8 pb0 = *(const bf16x8*)(&spb[(0 * 16 + m16) * SPBW + ks * 32 + quad * 8]);
    bf16x8 pb1 = *(const bf16x8*)(&spb[(1 * 16 + m16) * SPBW + ks * 32 + quad * 8]);
#pragma unroll
    for (int nt = 0; nt < 12; nt++) {
      const int d = w * 192 + nt * 16 + m16;
      bf16x8 vf = *(const bf16x8*)(vg + (size_t)d * 256 + ks * 32 + quad * 8);
      oaccT[nt][0] = __builtin_amdgcn_mfma_f32_16x16x32_bf16(vf, pb0, oaccT[nt][0], 0, 0, 0);
      oaccT[nt][1] = __builtin_amdgcn_mfma_f32_16x16x32_bf16(vf, pb1, oaccT[nt][1], 0, 0, 0);
    }
  }
  const float iv0 = inv[m16], iv1 = inv[16 + m16];
  const size_t rowg = (size_t)b * NQ + n0;
#pragma unroll
  for (int nt = 0; nt < 12; nt++) {
#pragma unroll
    for (int rr = 0; rr < 4; rr++) {
      const int d = w * 192 + nt * 16 + quad * 4 + rr;
      const size_t base = ((size_t)(d & 15) * 384 + h * 48 + (d >> 4)) * 8192 + rowg;
      ctxT[base + m16] = f2bf(oaccT[nt][0][rr] * iv0);
      ctxT[base + 16 + m16] = f2bf(oaccT[nt][1][rr] * iv1);
    }
  }
}

// ---------------------------------------------------------------------------
// out_kernel v3: block 1024 = 16 waves (wave = component c, lane = row).
// grid (128, 2), y-split over 24 of 48 channels.  Main loop: straight
// coalesced ctxT reads + wave-uniform scalar weights — no LDS, no barriers.
// Epilogue (R6-proven): acc -> LDS -> contiguous float4 + residual.
// ---------------------------------------------------------------------------
#define ESTR 388
__global__ __launch_bounds__(1024) void out_kernel(
    const u16* __restrict__ ctxT, const float* __restrict__ Wo,
    const float* __restrict__ bo, const float* __restrict__ hidden,
    float* __restrict__ out) {
  __shared__ __align__(16) float es[16 * ESTR];  // 24.8 KB
  const int t = threadIdx.x;
  const int c = __builtin_amdgcn_readfirstlane(t >> 6);
  const int lane = t & 63;
  const int row0 = blockIdx.x * 64;
  const int row = row0 + lane;
  const int ob = blockIdx.y * 24;
  const int g = grade_of(c);
  float acc[24];
#pragma unroll
  for (int o = 0; o < 24; o++) acc[o] = 0.f;

  const u16* xp = ctxT + (size_t)c * 384 * 8192 + row;
  for (int ib = 0; ib < 24; ib++) {
    float xv[16];
#pragma unroll
    for (int ii = 0; ii < 16; ii++) xv[ii] = bf2f(xp[(size_t)(ib * 16 + ii) * 8192]);
#pragma unroll 4
    for (int o = 0; o < 24; o++) {
      const float* wr = Wo + ((size_t)g * 48 + ob + o) * 384 + ib * 16;  // uniform
      float a = 0.f;
#pragma unroll
      for (int ii = 0; ii < 16; ii++) a += xv[ii] * wr[ii];
      acc[o] += a;
    }
  }
  if (c == 0) {
#pragma unroll
    for (int o = 0; o < 24; o++) acc[o] += bo[ob + o];
  }

  for (int chunk = 0; chunk < 4; chunk++) {
    __syncthreads();
    if ((lane >> 4) == chunk) {
      const int r16 = lane & 15;
#pragma unroll
      for (int o = 0; o < 24; o++) es[r16 * ESTR + o * 16 + c] = acc[o];
    }
    __syncthreads();
    for (int m = t; m < 1536; m += 1024) {
      int r = m / 96, col = m - r * 96;
      float4 v = *(const float4*)&es[r * ESTR + col * 4];
      size_t gidx = (size_t)(row0 + chunk * 16 + r) * 768 + ob * 16 + col * 4;
      const float4 hv = *(const float4*)&hidden[gidx];
      v.x += hv.x; v.y += hv.y; v.z += hv.z; v.w += hv.w;
      *(float4*)&out[gidx] = v;
    }
  }
}

// ---------------------------------------------------------------------------
extern "C" void kernel_launch(void* const* d_in, const int* in_sizes, int n_in,
                              void* d_out, int out_size, void* d_ws, size_t ws_size,
                              hipStream_t stream) {
  const float* hidden = (const float*)d_in[0];
  const float* vis = (const float*)d_in[1];
  const float* lnw = (const float*)d_in[2];
  const float* Wq = (const float*)d_in[3];
  const float* bq = (const float*)d_in[4];
  const float* Wkv = (const float*)d_in[5];
  const float* bkv = (const float*)d_in[6];
  const float* Wo = (const float*)d_in[7];
  const float* bo = (const float*)d_in[8];
  const float* daa = (const float*)d_in[9];
  float* out = (float*)d_out;

  char* ws = (char*)d_ws;
  size_t off = 0;
  auto carve = [&](size_t bytes) -> void* {
    void* p = ws + off;
    off += (bytes + 255) & ~(size_t)255;
    return p;
  };
  float* rscale = (float*)carve((size_t)BB * NQ * 4);
  float* WqT = (float*)carve((size_t)5 * 48 * 384 * 4);
  float* WkvT = (float*)carve((size_t)5 * 48 * 768 * 4);
  u16* qsel = (u16*)carve((size_t)BB * HH * NQ * KD * 2);
  u16* ksel = (u16*)carve((size_t)BB * HH * NK * KD * 2);
  u16* vT = (u16*)carve((size_t)BB * HH * 768 * 256 * 2);
  float* kbias = (float*)carve((size_t)BB * HH * NK * 4);
  // union: [hTn | visT] (transposed inputs, consumed by q/kv) then ctxT
  char* uni = (char*)carve((size_t)16 * 384 * 8192 * 2);  // 100.7 MB
  u16* ctxT = (u16*)uni;
  float* hTn = (float*)uni;                                // 25.2 MB
  float* visT = (float*)(uni + (size_t)16 * 48 * 8192 * 4); // 6.3 MB

  rms_kernel<<<BB * NQ / 32, 256, 0, stream>>>(hidden, rscale);
  wT_kernel<<<1080, 256, 0, stream>>>(Wq, Wkv, WqT, WkvT);
  xT_kernel<<<BB * NQ / 64, 256, 0, stream>>>(hidden, hTn, rscale, lnw, BB * NQ, 1);
  xT_kernel<<<BB * NK / 64, 256, 0, stream>>>(vis, visT, nullptr, nullptr, BB * NK, 0);
  kv_kernel<<<dim3(BB * NK / 64, 7, 2), 256, 0, stream>>>(visT, WkvT, bkv, daa, ksel, kbias, vT);
  q_kernel<<<dim3(BB * NQ / 64, 3, 2), 256, 0, stream>>>(hTn, WqT, bq, daa, qsel);
  attn_kernel<<<dim3(NQ / 32, HH, BB), 256, 0, stream>>>(qsel, ksel, kbias, vT, ctxT);
  out_kernel<<<dim3(BB * NQ / 64, 2), 1024, 0, stream>>>(ctxT, Wo, bo, hidden, out);
}

// Round 8
// 696.885 us; speedup vs baseline: 4.1255x; 1.2436x over previous
//
#include <hip/hip_runtime.h>

typedef unsigned short u16;
typedef unsigned int u32;
typedef unsigned long long u64;

typedef float f32x4 __attribute__((ext_vector_type(4)));
typedef short bf16x8 __attribute__((ext_vector_type(8)));

#define BB 8
#define NQ 1024
#define NK 256
#define HH 8
#define KD 544   // padded score-dot length (11*48=528 -> 544 = 17*32)

__device__ __forceinline__ float bf2f(u16 u) {
  union { u32 i; float f; } v; v.i = ((u32)u) << 16; return v.f;
}
__device__ __forceinline__ u16 f2bf(float f) {
  union { u32 i; float f; } v; v.f = f;
  u32 i = v.i;
  return (u16)((i + 0x7FFFu + ((i >> 16) & 1u)) >> 16);
}
__device__ __forceinline__ float softplusf(float d) {
  return (d > 20.f) ? d : log1pf(__expf(d));
}

// grade per component c (GRADE_IDX), nibble-packed
#define GRADE_TAB 0x4333322222211110ULL
// active component for score-slot s (slots 0..10 = INNER(8) then POINT(3))
#define ACT_TAB   0xDCBEA984320ULL
__device__ __forceinline__ int grade_of(int c) { return (int)((GRADE_TAB >> (c * 4)) & 15ULL); }
__device__ __forceinline__ int act_of(int s) { return (int)((ACT_TAB >> (s * 4)) & 15ULL); }

constexpr float INV_S384 = 0.05103103630798288f; // 1/sqrt(8*48)

// ---------------------------------------------------------------------------
// rms_kernel: rscale[row] = rsqrt(mean_i sum_c x^2 /48 + eps). 32 rows/block.
// ---------------------------------------------------------------------------
__global__ __launch_bounds__(256) void rms_kernel(const float* __restrict__ hidden,
                                                  float* __restrict__ rscale) {
  const int t = threadIdx.x;
  const int row = blockIdx.x * 32 + (t >> 3);
  const int l = t & 7;
  const float4* src = (const float4*)(hidden + (size_t)row * 768);
  float s = 0.f;
#pragma unroll
  for (int k = 0; k < 24; k++) {
    float4 v = src[l + 8 * k];
    s += v.x * v.x + v.y * v.y + v.z * v.z + v.w * v.w;
  }
#pragma unroll
  for (int off = 4; off; off >>= 1) s += __shfl_xor(s, off, 8);
  if (l == 0) rscale[row] = rsqrtf(s * (1.f / 48.f) + 1e-6f);
}

// ---------------------------------------------------------------------------
// wT_kernel: WqT[g][i][o], WkvT[g][i][o] (f32 transposes) + WoB = bf16(Wo)
// (same [g][o][i] layout, for MFMA B-frags).  grid = 1440.
// ---------------------------------------------------------------------------
__global__ __launch_bounds__(256) void wT_kernel(const float* __restrict__ Wq,
                                                 const float* __restrict__ Wkv,
                                                 const float* __restrict__ Wo,
                                                 float* __restrict__ WqT,
                                                 float* __restrict__ WkvT,
                                                 u16* __restrict__ WoB) {
  int idx = blockIdx.x * 256 + threadIdx.x;
  const int NQT = 5 * 48 * 384;
  const int NKVT = 5 * 48 * 768;
  if (idx < NQT) {
    int g = idx / 18432;
    int rem = idx - g * 18432;
    int i = rem / 384, o = rem - i * 384;
    WqT[idx] = Wq[((size_t)g * 384 + o) * 48 + i];
  } else if (idx < NQT + NKVT) {
    int j = idx - NQT;
    int g = j / 36864;
    int rem = j - g * 36864;
    int i = rem / 768, o = rem - i * 768;
    WkvT[j] = Wkv[((size_t)g * 768 + o) * 48 + i];
  } else if (idx < NQT + NKVT + NQT) {
    int j = idx - NQT - NKVT;
    WoB[j] = f2bf(Wo[j]);
  }
}

// ---------------------------------------------------------------------------
// xT_kernel: x[row][i*16+c] -> xT[c][i][row] (f32), optional RMS*lnw fold.
// ---------------------------------------------------------------------------
__global__ __launch_bounds__(256) void xT_kernel(
    const float* __restrict__ src, float* __restrict__ dst,
    const float* __restrict__ rscale, const float* __restrict__ lnw,
    int NR, int norm) {
  __shared__ __align__(16) float ls[64 * 132];
  __shared__ float rs_s[64];
  const int t = threadIdx.x;
  const int row0 = blockIdx.x * 64;
  if (norm && t < 64) rs_s[t] = rscale[row0 + t];

  const int p = t >> 1, h2 = t & 1;
  const int c = p & 15, il = p >> 4;

  for (int ib = 0; ib < 6; ib++) {
    __syncthreads();
#pragma unroll
    for (int k = 0; k < 8; k++) {
      int idx = t + 256 * k;
      int r = idx >> 5, c4 = idx & 31;
      float4 v = *(const float4*)(src + (size_t)(row0 + r) * 768 + ib * 128 + c4 * 4);
      *(float4*)&ls[r * 132 + c4 * 4] = v;
    }
    __syncthreads();
    const int ig = ib * 8 + il;
    const float lw = norm ? lnw[ig] : 1.f;
    float vbuf[32];
#pragma unroll
    for (int j = 0; j < 32; j++) {
      float v = ls[(h2 * 32 + j) * 132 + il * 16 + c];
      if (norm) v *= rs_s[h2 * 32 + j] * lw;
      vbuf[j] = v;
    }
    float* dp = dst + ((size_t)c * 48 + ig) * NR + row0 + h2 * 32;
#pragma unroll
    for (int j4 = 0; j4 < 8; j4++) {
      float4 v4 = {vbuf[j4 * 4], vbuf[j4 * 4 + 1], vbuf[j4 * 4 + 2], vbuf[j4 * 4 + 3]};
      *(float4*)(dp + j4 * 4) = v4;
    }
  }
}

// ---------------------------------------------------------------------------
// q_kernel: wave = one active component c, lane = row; x from hTn (coalesced),
// weights via wave-uniform scalar loads.  grid = (128, 3, 2).
// ---------------------------------------------------------------------------
__global__ __launch_bounds__(256) void q_kernel(
    const float* __restrict__ hTn, const float* __restrict__ WqT,
    const float* __restrict__ bq, const float* __restrict__ daa,
    u16* __restrict__ qsel) {
  const int wid = __builtin_amdgcn_readfirstlane(threadIdx.x >> 6);
  const int task = blockIdx.y * 4 + wid;  // 0..11
  const int lane = threadIdx.x & 63;
  const int row = blockIdx.x * 64 + lane; // 0..8191
  const int b = row >> 10, n = row & 1023;
  const int o0 = blockIdx.z * 192;

  if (blockIdx.y == 0 && blockIdx.z == 0) {
    const int row0 = blockIdx.x * 64;
    const int bb = row0 >> 10, n0 = row0 & 1023;
    uint4 z4 = {0u, 0u, 0u, 0u};
    for (int m = threadIdx.x; m < 1024; m += 256) {
      int h = m >> 7, r = (m >> 1) & 63, half = m & 1;
      *(uint4*)(qsel + ((size_t)(bb * HH + h) * NQ + n0 + r) * KD + 528 + half * 8) = z4;
    }
  }
  if (task >= 11) return;

  const int c = act_of(task);
  const int slot = task;
  const int g = grade_of(c);
  float xr[48];
  const float* xsrc = hTn + (size_t)c * 48 * 8192 + row;
#pragma unroll
  for (int i = 0; i < 48; i++) xr[i] = xsrc[(size_t)i * 8192];
  const bool isc0 = (c == 0);

  for (int og = 0; og < 24; og++) {
    const int o = o0 + og * 8;   // 8 outputs, same h (48%8==0)
    const int h = o / 48;
    const int oc = o - h * 48;
    float acc[8];
#pragma unroll
    for (int k = 0; k < 8; k++) acc[k] = 0.f;
#pragma unroll 4
    for (int i = 0; i < 48; i++) {
      const float* wr = WqT + ((size_t)(g * 48 + i)) * 384 + o;  // wave-uniform
      const float xv = xr[i];
#pragma unroll
      for (int k = 0; k < 8; k++) acc[k] += xv * wr[k];
    }
    if (isc0) {
#pragma unroll
      for (int k = 0; k < 8; k++) acc[k] += bq[o + k];
    }
    const float sc = (slot < 8) ? INV_S384 : (2.f * softplusf(daa[h]) * (1.f / 48.f));
    u32 p0 = (u32)f2bf(acc[0] * sc) | ((u32)f2bf(acc[1] * sc) << 16);
    u32 p1 = (u32)f2bf(acc[2] * sc) | ((u32)f2bf(acc[3] * sc) << 16);
    u32 p2 = (u32)f2bf(acc[4] * sc) | ((u32)f2bf(acc[5] * sc) << 16);
    u32 p3 = (u32)f2bf(acc[6] * sc) | ((u32)f2bf(acc[7] * sc) << 16);
    uint4 pk = {p0, p1, p2, p3};
    *(uint4*)(qsel + ((size_t)(b * HH + h) * NQ + n) * KD + slot * 48 + oc) = pk;
  }
}

// ---------------------------------------------------------------------------
// kv_kernel: tasks 0..10 = k components, 11..26 = v components; x from visT
// (coalesced).  grid = (32, 7, 2).
// ---------------------------------------------------------------------------
__global__ __launch_bounds__(256) void kv_kernel(
    const float* __restrict__ visT, const float* __restrict__ WkvT,
    const float* __restrict__ bkv, const float* __restrict__ daa,
    u16* __restrict__ ksel, float* __restrict__ kbias, u16* __restrict__ vT) {
  __shared__ float k2s[64 * 8];
  const int wid = __builtin_amdgcn_readfirstlane(threadIdx.x >> 6);
  const int task = blockIdx.y * 4 + wid;  // 0..27
  const int lane = threadIdx.x & 63;
  const int row = blockIdx.x * 64 + lane; // 0..2047
  const int b = row >> 8, n = row & 255;
  const int o0 = blockIdx.z * 192;

  k2s[threadIdx.x] = 0.f;
  k2s[threadIdx.x + 256] = 0.f;
  __syncthreads();

  if (blockIdx.y == 0 && blockIdx.z == 0) {
    const int row0 = blockIdx.x * 64;
    const int bb = row0 >> 8, n0 = row0 & 255;
    uint4 z4 = {0u, 0u, 0u, 0u};
    for (int m = threadIdx.x; m < 1024; m += 256) {
      int h = m >> 7, r = (m >> 1) & 63, half = m & 1;
      *(uint4*)(ksel + ((size_t)(bb * HH + h) * NK + n0 + r) * KD + 528 + half * 8) = z4;
    }
  }

  if (task < 11) {  // k component
    const int c = act_of(task);
    const int slot = task;
    const int g = grade_of(c);
    float xr[48];
    const float* xsrc = visT + (size_t)c * 48 * 2048 + row;
#pragma unroll
    for (int i = 0; i < 48; i++) xr[i] = xsrc[(size_t)i * 2048];
    const bool isc0 = (c == 0);
    const bool ispt = (task >= 8);  // c in {11,12,13}
    for (int og = 0; og < 24; og++) {
      const int o = o0 + og * 8;
      const int h = o / 48, oc = o - h * 48;
      float acc[8];
#pragma unroll
      for (int k = 0; k < 8; k++) acc[k] = 0.f;
#pragma unroll 4
      for (int i = 0; i < 48; i++) {
        const float* wr = WkvT + ((size_t)(g * 48 + i)) * 768 + o;
        const float xv = xr[i];
#pragma unroll
        for (int k = 0; k < 8; k++) acc[k] += xv * wr[k];
      }
      if (isc0) {
#pragma unroll
        for (int k = 0; k < 8; k++) acc[k] += bkv[o + k];
      }
      u32 p0 = (u32)f2bf(acc[0]) | ((u32)f2bf(acc[1]) << 16);
      u32 p1 = (u32)f2bf(acc[2]) | ((u32)f2bf(acc[3]) << 16);
      u32 p2 = (u32)f2bf(acc[4]) | ((u32)f2bf(acc[5]) << 16);
      u32 p3 = (u32)f2bf(acc[6]) | ((u32)f2bf(acc[7]) << 16);
      uint4 pk = {p0, p1, p2, p3};
      *(uint4*)(ksel + ((size_t)(b * HH + h) * NK + n) * KD + slot * 48 + oc) = pk;
      if (ispt) {
        float s2 = 0.f;
#pragma unroll
        for (int k = 0; k < 8; k++) s2 += acc[k] * acc[k];
        atomicAdd(&k2s[lane * 8 + h], s2);
      }
    }
  } else if (task < 27) {  // v component
    const int c = task - 11;
    const int g = grade_of(c);
    float xr[48];
    const float* xsrc = visT + (size_t)c * 48 * 2048 + row;
#pragma unroll
    for (int i = 0; i < 48; i++) xr[i] = xsrc[(size_t)i * 2048];
    const bool isc0 = (c == 0);
    for (int og = 0; og < 24; og++) {
      const int o = o0 + og * 8;  // o2
      const int h = o / 48, oc = o - h * 48;
      float acc[8];
#pragma unroll
      for (int k = 0; k < 8; k++) acc[k] = 0.f;
#pragma unroll 4
      for (int i = 0; i < 48; i++) {
        const float* wr = WkvT + ((size_t)(g * 48 + i)) * 768 + 384 + o;
        const float xv = xr[i];
#pragma unroll
        for (int k = 0; k < 8; k++) acc[k] += xv * wr[k];
      }
      if (isc0) {
#pragma unroll
        for (int k = 0; k < 8; k++) acc[k] += bkv[384 + o + k];
      }
#pragma unroll
      for (int k = 0; k < 8; k++)
        vT[((size_t)(b * HH + h) * 768 + (oc + k) * 16 + c) * 256 + n] = f2bf(acc[k]);
    }
  }
  __syncthreads();
  if (blockIdx.y == 2) {
    const int row0 = blockIdx.x * 64;
    const int bb = row0 >> 8, n0 = row0 & 255;
    int m = threadIdx.x;  // 256 = 64 rows x 4 h
    int rr = m >> 2, h = blockIdx.z * 4 + (m & 3);
    kbias[(size_t)(bb * HH + h) * NK + n0 + rr] =
        -(softplusf(daa[h]) * (1.f / 48.f)) * k2s[rr * 8 + h];
  }
}

// ---------------------------------------------------------------------------
// MFMA attention.  Scores unchanged.  PV = D[m=q-row][n=d] (R4 verified);
// store ctxJ[c][row_global][i=h*48+oc] — per lane 12 consecutive u16
// (c = m16 fixed per lane, i = h*48 + w*12 + nt), 3x 8B stores.
// ---------------------------------------------------------------------------
#define SPW 260
#define SPBW 264
__global__ __launch_bounds__(256) void attn_kernel(
    const u16* __restrict__ qsel, const u16* __restrict__ ksel,
    const float* __restrict__ kbias, const u16* __restrict__ vT,
    u16* __restrict__ ctxJ) {
  const int qt = blockIdx.x, h = blockIdx.y, b = blockIdx.z;
  const int t = threadIdx.x;
  const int w = t >> 6;
  const int lane = t & 63;
  const int m16 = lane & 15;
  const int quad = lane >> 4;

  __shared__ __align__(16) float sp[32 * SPW];
  __shared__ __align__(16) u16 spb[32 * SPBW];
  __shared__ float kb[256];
  __shared__ float inv[32];

  const size_t bh = (size_t)(b * HH + h);
  const int n0 = qt * 32;
  const u16* qg = qsel + (bh * NQ + n0) * KD;
  const u16* kg = ksel + bh * NK * KD;
  const u16* vg = vT + bh * 768 * 256;

  kb[t] = kbias[bh * NK + t];

  f32x4 sacc[2][4];
#pragma unroll
  for (int mt = 0; mt < 2; mt++)
#pragma unroll
    for (int nt = 0; nt < 4; nt++) sacc[mt][nt] = (f32x4)0.f;

  for (int ks = 0; ks < 17; ks++) {
    bf16x8 qa0 = *(const bf16x8*)(qg + (size_t)(0 * 16 + m16) * KD + ks * 32 + quad * 8);
    bf16x8 qa1 = *(const bf16x8*)(qg + (size_t)(1 * 16 + m16) * KD + ks * 32 + quad * 8);
#pragma unroll
    for (int nt = 0; nt < 4; nt++) {
      bf16x8 kf = *(const bf16x8*)(kg + (size_t)(w * 64 + nt * 16 + m16) * KD + ks * 32 + quad * 8);
      sacc[0][nt] = __builtin_amdgcn_mfma_f32_16x16x32_bf16(qa0, kf, sacc[0][nt], 0, 0, 0);
      sacc[1][nt] = __builtin_amdgcn_mfma_f32_16x16x32_bf16(qa1, kf, sacc[1][nt], 0, 0, 0);
    }
  }
#pragma unroll
  for (int mt = 0; mt < 2; mt++)
#pragma unroll
    for (int nt = 0; nt < 4; nt++)
#pragma unroll
      for (int rr = 0; rr < 4; rr++)
        sp[(mt * 16 + quad * 4 + rr) * SPW + w * 64 + nt * 16 + m16] = sacc[mt][nt][rr];
  __syncthreads();

  {
    const int rr = t >> 3, cg = t & 7;
    float vals[32];
    float mx = -1e30f;
#pragma unroll
    for (int i = 0; i < 32; i++) {
      int k = cg + 8 * i;
      float v = sp[rr * SPW + k] + kb[k];
      vals[i] = v;
      mx = fmaxf(mx, v);
    }
#pragma unroll
    for (int off = 4; off; off >>= 1) mx = fmaxf(mx, __shfl_xor(mx, off, 8));
    float s = 0.f;
#pragma unroll
    for (int i = 0; i < 32; i++) {
      float e = __expf(vals[i] - mx);
      s += e;
      spb[rr * SPBW + cg + 8 * i] = f2bf(e);
    }
#pragma unroll
    for (int off = 4; off; off >>= 1) s += __shfl_xor(s, off, 8);
    if (cg == 0) inv[rr] = 1.f / s;
  }
  __syncthreads();

  // ---- PV: D[m=q-row][n=d] ----
  f32x4 oacc[2][12];
#pragma unroll
  for (int mt = 0; mt < 2; mt++)
#pragma unroll
    for (int nt = 0; nt < 12; nt++) oacc[mt][nt] = (f32x4)0.f;

  for (int ks = 0; ks < 8; ks++) {
    bf16x8 pa0 = *(const bf16x8*)(&spb[(0 * 16 + m16) * SPBW + ks * 32 + quad * 8]);
    bf16x8 pa1 = *(const bf16x8*)(&spb[(1 * 16 + m16) * SPBW + ks * 32 + quad * 8]);
#pragma unroll
    for (int nt = 0; nt < 12; nt++) {
      const int d = w * 192 + nt * 16 + m16;
      bf16x8 vf = *(const bf16x8*)(vg + (size_t)d * 256 + ks * 32 + quad * 8);
      oacc[0][nt] = __builtin_amdgcn_mfma_f32_16x16x32_bf16(pa0, vf, oacc[0][nt], 0, 0, 0);
      oacc[1][nt] = __builtin_amdgcn_mfma_f32_16x16x32_bf16(pa1, vf, oacc[1][nt], 0, 0, 0);
    }
  }
  // store: c = m16, i = h*48 + w*12 + nt (12 contiguous u16 per lane)
  const size_t rowbase = (size_t)b * NQ + n0;
#pragma unroll
  for (int mt = 0; mt < 2; mt++)
#pragma unroll
    for (int rr = 0; rr < 4; rr++) {
      const int row = mt * 16 + quad * 4 + rr;
      const float iv = inv[row];
      u32 pk[6];
#pragma unroll
      for (int j = 0; j < 6; j++) {
        u32 lo = f2bf(oacc[mt][2 * j][rr] * iv);
        u32 hi = f2bf(oacc[mt][2 * j + 1][rr] * iv);
        pk[j] = lo | (hi << 16);
      }
      u16* dst = ctxJ + ((size_t)m16 * 8192 + rowbase + row) * 384 + h * 48 + w * 12;
#pragma unroll
      for (int q3 = 0; q3 < 3; q3++) {
        uint2 uv = {pk[2 * q3], pk[2 * q3 + 1]};
        *(uint2*)(dst + q3 * 4) = uv;
      }
    }
}

// ---------------------------------------------------------------------------
// out_kernel v4 (MFMA): block 1024 = 16 waves, wave = component c.
// grid = 256 (32-row tiles, 2 chunks of 16).  Per chunk: wave computes
// D[16 rows][48 o] = ctxJ[c] rows (A) x WoB[g(c)] rows (B), K=384.
// Epilogue: D -> padded LDS (c*49+o, row stride 785; <=2-way banks) ->
// coalesced float4 out + residual + bias.  OUTPUT fp32.
// ---------------------------------------------------------------------------
#define ESTR2 785
__global__ __launch_bounds__(1024) void out_kernel(
    const u16* __restrict__ ctxJ, const u16* __restrict__ WoB,
    const float* __restrict__ bo, const float* __restrict__ hidden,
    float* __restrict__ out) {
  __shared__ __align__(16) float es[16 * ESTR2];  // 50.2 KB
  const int t = threadIdx.x;
  const int c = __builtin_amdgcn_readfirstlane(t >> 6);
  const int lane = t & 63;
  const int m16 = lane & 15, quad = lane >> 4;
  const int row0 = blockIdx.x * 32;
  const int g = grade_of(c);
  const u16* wb = WoB + (size_t)g * 48 * 384;

  for (int ch = 0; ch < 2; ch++) {
    const int r0 = row0 + ch * 16;
    f32x4 acc[3];
#pragma unroll
    for (int nt = 0; nt < 3; nt++) acc[nt] = (f32x4)0.f;
    const u16* ap = ctxJ + ((size_t)c * 8192 + r0 + m16) * 384 + quad * 8;
#pragma unroll 4
    for (int ks = 0; ks < 12; ks++) {
      bf16x8 af = *(const bf16x8*)(ap + ks * 32);
#pragma unroll
      for (int nt = 0; nt < 3; nt++) {
        bf16x8 bf = *(const bf16x8*)(wb + (size_t)(nt * 16 + m16) * 384 + ks * 32 + quad * 8);
        acc[nt] = __builtin_amdgcn_mfma_f32_16x16x32_bf16(af, bf, acc[nt], 0, 0, 0);
      }
    }
    __syncthreads();
#pragma unroll
    for (int nt = 0; nt < 3; nt++)
#pragma unroll
      for (int rr = 0; rr < 4; rr++)
        es[(quad * 4 + rr) * ESTR2 + c * 49 + nt * 16 + m16] = acc[nt][rr];
    __syncthreads();
#pragma unroll
    for (int k = 0; k < 3; k++) {
      int m4 = t + 1024 * k;          // 3072 float4 groups = 16 rows x 768
      int r = m4 / 192;
      int col0 = (m4 - r * 192) * 4;  // col = o*16 + c_out
      int o = col0 >> 4, cb = col0 & 15;
      const float* er = &es[r * ESTR2 + o];
      float4 v;
      v.x = er[(cb + 0) * 49];
      v.y = er[(cb + 1) * 49];
      v.z = er[(cb + 2) * 49];
      v.w = er[(cb + 3) * 49];
      if (cb == 0) v.x += bo[o];
      size_t gidx = (size_t)(r0 + r) * 768 + col0;
      const float4 hv = *(const float4*)&hidden[gidx];
      v.x += hv.x; v.y += hv.y; v.z += hv.z; v.w += hv.w;
      *(float4*)&out[gidx] = v;
    }
  }
}

// ---------------------------------------------------------------------------
extern "C" void kernel_launch(void* const* d_in, const int* in_sizes, int n_in,
                              void* d_out, int out_size, void* d_ws, size_t ws_size,
                              hipStream_t stream) {
  const float* hidden = (const float*)d_in[0];
  const float* vis = (const float*)d_in[1];
  const float* lnw = (const float*)d_in[2];
  const float* Wq = (const float*)d_in[3];
  const float* bq = (const float*)d_in[4];
  const float* Wkv = (const float*)d_in[5];
  const float* bkv = (const float*)d_in[6];
  const float* Wo = (const float*)d_in[7];
  const float* bo = (const float*)d_in[8];
  const float* daa = (const float*)d_in[9];
  float* out = (float*)d_out;

  char* ws = (char*)d_ws;
  size_t off = 0;
  auto carve = [&](size_t bytes) -> void* {
    void* p = ws + off;
    off += (bytes + 255) & ~(size_t)255;
    return p;
  };
  float* rscale = (float*)carve((size_t)BB * NQ * 4);
  float* WqT = (float*)carve((size_t)5 * 48 * 384 * 4);
  float* WkvT = (float*)carve((size_t)5 * 48 * 768 * 4);
  u16* WoB = (u16*)carve((size_t)5 * 48 * 384 * 2);
  u16* qsel = (u16*)carve((size_t)BB * HH * NQ * KD * 2);
  u16* ksel = (u16*)carve((size_t)BB * HH * NK * KD * 2);
  u16* vT = (u16*)carve((size_t)BB * HH * 768 * 256 * 2);
  float* kbias = (float*)carve((size_t)BB * HH * NK * 4);
  // union: [hTn | visT] (transposed inputs, consumed by q/kv) then ctxJ
  char* uni = (char*)carve((size_t)16 * 384 * 8192 * 2);  // 100.7 MB
  u16* ctxJ = (u16*)uni;
  float* hTn = (float*)uni;                                 // 25.2 MB
  float* visT = (float*)(uni + (size_t)16 * 48 * 8192 * 4); // 6.3 MB

  rms_kernel<<<BB * NQ / 32, 256, 0, stream>>>(hidden, rscale);
  wT_kernel<<<1440, 256, 0, stream>>>(Wq, Wkv, Wo, WqT, WkvT, WoB);
  xT_kernel<<<BB * NQ / 64, 256, 0, stream>>>(hidden, hTn, rscale, lnw, BB * NQ, 1);
  xT_kernel<<<BB * NK / 64, 256, 0, stream>>>(vis, visT, nullptr, nullptr, BB * NK, 0);
  kv_kernel<<<dim3(BB * NK / 64, 7, 2), 256, 0, stream>>>(visT, WkvT, bkv, daa, ksel, kbias, vT);
  q_kernel<<<dim3(BB * NQ / 64, 3, 2), 256, 0, stream>>>(hTn, WqT, bq, daa, qsel);
  attn_kernel<<<dim3(NQ / 32, HH, BB), 256, 0, stream>>>(qsel, ksel, kbias, vT, ctxJ);
  out_kernel<<<256, 1024, 0, stream>>>(ctxJ, WoB, bo, hidden, out);
}

// Round 9
// 509.287 us; speedup vs baseline: 5.6452x; 1.3684x over previous
//
#include <hip/hip_runtime.h>

typedef unsigned short u16;
typedef unsigned int u32;
typedef unsigned long long u64;

typedef float f32x4 __attribute__((ext_vector_type(4)));
typedef short bf16x8 __attribute__((ext_vector_type(8)));

#define BB 8
#define NQ 1024
#define NK 256
#define HH 8
#define KD 544   // padded score-dot length (11*48=528 -> 544 = 17*32)

__device__ __forceinline__ float bf2f(u16 u) {
  union { u32 i; float f; } v; v.i = ((u32)u) << 16; return v.f;
}
__device__ __forceinline__ u16 f2bf(float f) {
  union { u32 i; float f; } v; v.f = f;
  u32 i = v.i;
  return (u16)((i + 0x7FFFu + ((i >> 16) & 1u)) >> 16);
}
__device__ __forceinline__ float softplusf(float d) {
  return (d > 20.f) ? d : log1pf(__expf(d));
}

// grade per component c (GRADE_IDX), nibble-packed
#define GRADE_TAB 0x4333322222211110ULL
// active component for score-slot s (slots 0..10 = INNER(8) then POINT(3))
#define ACT_TAB   0xDCBEA984320ULL
__device__ __forceinline__ int grade_of(int c) { return (int)((GRADE_TAB >> (c * 4)) & 15ULL); }
__device__ __forceinline__ int act_of(int s) { return (int)((ACT_TAB >> (s * 4)) & 15ULL); }

constexpr float INV_S384 = 0.05103103630798288f; // 1/sqrt(8*48)

// ---------------------------------------------------------------------------
// rms_kernel: rscale[row] = rsqrt(mean_i sum_c x^2 /48 + eps). 32 rows/block.
// ---------------------------------------------------------------------------
__global__ __launch_bounds__(256) void rms_kernel(const float* __restrict__ hidden,
                                                  float* __restrict__ rscale) {
  const int t = threadIdx.x;
  const int row = blockIdx.x * 32 + (t >> 3);
  const int l = t & 7;
  const float4* src = (const float4*)(hidden + (size_t)row * 768);
  float s = 0.f;
#pragma unroll
  for (int k = 0; k < 24; k++) {
    float4 v = src[l + 8 * k];
    s += v.x * v.x + v.y * v.y + v.z * v.z + v.w * v.w;
  }
#pragma unroll
  for (int off = 4; off; off >>= 1) s += __shfl_xor(s, off, 8);
  if (l == 0) rscale[row] = rsqrtf(s * (1.f / 48.f) + 1e-6f);
}

// ---------------------------------------------------------------------------
// wB_kernel: WqB[g][o][64] / WkvB[g][o][64] bf16 (K padded 48->64, zeros) for
// MFMA B-frags; WoB = bf16(Wo) (K=384 layout, unchanged).
// ---------------------------------------------------------------------------
__global__ __launch_bounds__(256) void wB_kernel(
    const float* __restrict__ Wq, const float* __restrict__ Wkv,
    const float* __restrict__ Wo, u16* __restrict__ WqB,
    u16* __restrict__ WkvB, u16* __restrict__ WoB) {
  int idx = blockIdx.x * 256 + threadIdx.x;
  const int NA = 5 * 384 * 64, NB = 5 * 768 * 64, NC = 5 * 48 * 384;
  if (idx < NA) {
    int g = idx / (384 * 64);
    int rem = idx - g * 384 * 64;
    int o = rem >> 6, j = rem & 63;
    WqB[idx] = (j < 48) ? f2bf(Wq[((size_t)g * 384 + o) * 48 + j]) : (u16)0;
  } else if (idx < NA + NB) {
    int k = idx - NA;
    int g = k / (768 * 64);
    int rem = k - g * 768 * 64;
    int o = rem >> 6, j = rem & 63;
    WkvB[k] = (j < 48) ? f2bf(Wkv[((size_t)g * 768 + o) * 48 + j]) : (u16)0;
  } else if (idx < NA + NB + NC) {
    int k = idx - NA - NB;
    WoB[k] = f2bf(Wo[k]);
  }
}

// ---------------------------------------------------------------------------
// xJ_kernel: x[row][i*16+c] (f32) -> xJ[c][row][64] bf16 (48 real i + 16 zero
// pad), optional RMS*lnw fold.  block = 64 rows via 4 chunks of 16.
// ---------------------------------------------------------------------------
__global__ __launch_bounds__(256) void xJ_kernel(
    const float* __restrict__ src, u16* __restrict__ dst,
    const float* __restrict__ rscale, const float* __restrict__ lnw,
    int NR, int norm) {
  __shared__ __align__(16) float ls[16 * 772];
  __shared__ float rs_s[16];
  const int t = threadIdx.x;
  const int row0 = blockIdx.x * 64;
  const int row16 = t & 15, c = t >> 4;
  for (int chunk = 0; chunk < 4; chunk++) {
    const int r0c = row0 + chunk * 16;
    __syncthreads();
    if (t < 16) rs_s[t] = norm ? rscale[r0c + t] : 1.f;
#pragma unroll
    for (int k = 0; k < 12; k++) {
      int f = t + 256 * k;
      int r = f / 192, j = f - r * 192;
      *(float4*)&ls[r * 772 + j * 4] =
          *(const float4*)(src + (size_t)(r0c + r) * 768 + j * 4);
    }
    __syncthreads();
    const float rsv = rs_s[row16];
    u16 buf[64];
#pragma unroll
    for (int i = 0; i < 48; i++) {
      float v = ls[row16 * 772 + i * 16 + c];
      if (norm) v *= rsv * lnw[i];
      buf[i] = f2bf(v);
    }
#pragma unroll
    for (int i = 48; i < 64; i++) buf[i] = 0;
    u16* dp = dst + ((size_t)c * NR + r0c + row16) * 64;
#pragma unroll
    for (int j4 = 0; j4 < 8; j4++) *(uint4*)(dp + j4 * 8) = *(uint4*)&buf[j4 * 8];
  }
}

// ---------------------------------------------------------------------------
// q_mfma: grid (128 rowblks of 64, 11 slots).  D[64 rows][384 o] = xq[c] (A)
// x WqB[g] (B), K=64.  Epilogue: scale(+bias) -> LDS -> 96B row-chunk stores
// into qsel (slot-10 blocks also zero the [528,544) pad).
// ---------------------------------------------------------------------------
#define QSTR 392
__global__ __launch_bounds__(256) void q_mfma(
    const u16* __restrict__ xq, const u16* __restrict__ WqB,
    const float* __restrict__ bq, const float* __restrict__ daa,
    u16* __restrict__ qsel) {
  __shared__ __align__(16) u16 es[4 * 16 * QSTR];  // 50.2 KB
  const int t = threadIdx.x;
  const int w = t >> 6, lane = t & 63, m16 = lane & 15, quad = lane >> 4;
  const int slot = blockIdx.y;
  const int c = act_of(slot), g = grade_of(c);
  const int row0 = blockIdx.x * 64;
  const int b = row0 >> 10, n0 = row0 & 1023;
  f32x4 acc[24];
#pragma unroll
  for (int nt = 0; nt < 24; nt++) acc[nt] = (f32x4)0.f;
  const u16* ap = xq + ((size_t)c * 8192 + row0 + w * 16 + m16) * 64 + quad * 8;
  const u16* wb = WqB + (size_t)g * 384 * 64 + (size_t)m16 * 64 + quad * 8;
#pragma unroll
  for (int ks = 0; ks < 2; ks++) {
    bf16x8 af = *(const bf16x8*)(ap + ks * 32);
#pragma unroll
    for (int nt = 0; nt < 24; nt++) {
      bf16x8 bf = *(const bf16x8*)(wb + (size_t)nt * 16 * 64 + ks * 32);
      acc[nt] = __builtin_amdgcn_mfma_f32_16x16x32_bf16(af, bf, acc[nt], 0, 0, 0);
    }
  }
#pragma unroll
  for (int nt = 0; nt < 24; nt++) {
    const int o = nt * 16 + m16;
    const int h = o / 48;
    const float sc = (slot < 8) ? INV_S384 : (2.f * softplusf(daa[h]) * (1.f / 48.f));
    const float bias = (slot == 0) ? bq[o] : 0.f;
#pragma unroll
    for (int rr = 0; rr < 4; rr++)
      es[(w * 16 + quad * 4 + rr) * QSTR + o] = f2bf((acc[nt][rr] + bias) * sc);
  }
  __syncthreads();
  for (int ch = t; ch < 512; ch += 256) {
    int r = ch >> 3, h = ch & 7;
    const uint4* sr = (const uint4*)&es[r * QSTR + h * 48];
    u16* dst = qsel + ((size_t)(b * 8 + h) * NQ + n0 + r) * KD + slot * 48;
#pragma unroll
    for (int j = 0; j < 6; j++) ((uint4*)dst)[j] = sr[j];
    if (slot == 10) {
      uint4 z = {0u, 0u, 0u, 0u};
      ((uint4*)dst)[6] = z;  // [528,536)
      ((uint4*)dst)[7] = z;  // [536,544)
    }
  }
}

// ---------------------------------------------------------------------------
// kv_mfma: grid (32 keyblks of 64, 27 tasks).  task<11: k-slot -> ksel (same
// structure as q_mfma, no scale).  task>=11: v component c=task-11 -> vT via
// [o][key] LDS staging (stride 72) and 8B key-contiguous stores.
// ---------------------------------------------------------------------------
#define VSTR 72
__global__ __launch_bounds__(256) void kv_mfma(
    const u16* __restrict__ xv, const u16* __restrict__ WkvB,
    const float* __restrict__ bkv, u16* __restrict__ ksel,
    u16* __restrict__ vT) {
  __shared__ __align__(16) u16 es[384 * VSTR];  // 55.3 KB (covers both uses)
  const int t = threadIdx.x;
  const int w = t >> 6, lane = t & 63, m16 = lane & 15, quad = lane >> 4;
  const int task = blockIdx.y;
  const int row0 = blockIdx.x * 64;
  const int b = row0 >> 8, n0 = row0 & 255;

  if (task < 11) {
    const int c = act_of(task), g = grade_of(c);
    f32x4 acc[24];
#pragma unroll
    for (int nt = 0; nt < 24; nt++) acc[nt] = (f32x4)0.f;
    const u16* ap = xv + ((size_t)c * 2048 + row0 + w * 16 + m16) * 64 + quad * 8;
    const u16* wb = WkvB + (size_t)g * 768 * 64 + (size_t)m16 * 64 + quad * 8;
#pragma unroll
    for (int ks = 0; ks < 2; ks++) {
      bf16x8 af = *(const bf16x8*)(ap + ks * 32);
#pragma unroll
      for (int nt = 0; nt < 24; nt++) {
        bf16x8 bf = *(const bf16x8*)(wb + (size_t)nt * 16 * 64 + ks * 32);
        acc[nt] = __builtin_amdgcn_mfma_f32_16x16x32_bf16(af, bf, acc[nt], 0, 0, 0);
      }
    }
#pragma unroll
    for (int nt = 0; nt < 24; nt++) {
      const int o = nt * 16 + m16;
      const float bias = (task == 0) ? bkv[o] : 0.f;
#pragma unroll
      for (int rr = 0; rr < 4; rr++)
        es[(w * 16 + quad * 4 + rr) * QSTR + o] = f2bf(acc[nt][rr] + bias);
    }
    __syncthreads();
    for (int ch = t; ch < 512; ch += 256) {
      int r = ch >> 3, h = ch & 7;
      const uint4* sr = (const uint4*)&es[r * QSTR + h * 48];
      u16* dst = ksel + ((size_t)(b * 8 + h) * NK + n0 + r) * KD + task * 48;
#pragma unroll
      for (int j = 0; j < 6; j++) ((uint4*)dst)[j] = sr[j];
      if (task == 10) {
        uint4 z = {0u, 0u, 0u, 0u};
        ((uint4*)dst)[6] = z;
        ((uint4*)dst)[7] = z;
      }
    }
  } else {
    const int c = task - 11, g = grade_of(c);
    f32x4 acc[24];
#pragma unroll
    for (int nt = 0; nt < 24; nt++) acc[nt] = (f32x4)0.f;
    const u16* ap = xv + ((size_t)c * 2048 + row0 + w * 16 + m16) * 64 + quad * 8;
    const u16* wb = WkvB + (size_t)g * 768 * 64 + (size_t)(384 + m16) * 64 + quad * 8;
#pragma unroll
    for (int ks = 0; ks < 2; ks++) {
      bf16x8 af = *(const bf16x8*)(ap + ks * 32);
#pragma unroll
      for (int nt = 0; nt < 24; nt++) {
        bf16x8 bf = *(const bf16x8*)(wb + (size_t)nt * 16 * 64 + ks * 32);
        acc[nt] = __builtin_amdgcn_mfma_f32_16x16x32_bf16(af, bf, acc[nt], 0, 0, 0);
      }
    }
#pragma unroll
    for (int nt = 0; nt < 24; nt++) {
      const int o = nt * 16 + m16;
      const float bias = (c == 0) ? bkv[384 + o] : 0.f;
#pragma unroll
      for (int rr = 0; rr < 4; rr++)
        es[o * VSTR + w * 16 + quad * 4 + rr] = f2bf(acc[nt][rr] + bias);
    }
    __syncthreads();
    for (int id = t; id < 6144; id += 256) {
      int o = id >> 4, part = id & 15;
      uint2 v = *(const uint2*)&es[o * VSTR + part * 4];
      int h = o / 48, oc = o - h * 48;
      *(uint2*)(vT + ((size_t)(b * 8 + h) * 768 + oc * 16 + c) * 256 + n0 + part * 4) = v;
    }
  }
}

// ---------------------------------------------------------------------------
// k2_kernel: kbias[bh*256+key] = -softplus(daa[h])/48 * sum(point k^2).
// Point slice is contiguous in ksel at [384,528).
// ---------------------------------------------------------------------------
__global__ __launch_bounds__(256) void k2_kernel(const u16* __restrict__ ksel,
                                                 const float* __restrict__ daa,
                                                 float* __restrict__ kbias) {
  int id = blockIdx.x * 256 + threadIdx.x;  // bh*256+key, < 16384
  const uint4* p = (const uint4*)(ksel + (size_t)id * KD + 384);
  float s = 0.f;
#pragma unroll
  for (int j = 0; j < 18; j++) {
    uint4 v = p[j];
    u32 a[4] = {v.x, v.y, v.z, v.w};
#pragma unroll
    for (int q = 0; q < 4; q++) {
      float lo = bf2f((u16)(a[q] & 0xFFFFu));
      float hi = bf2f((u16)(a[q] >> 16));
      s += lo * lo + hi * hi;
    }
  }
  int h = (id >> 8) & 7;
  kbias[id] = -(softplusf(daa[h]) * (1.f / 48.f)) * s;
}

// ---------------------------------------------------------------------------
// MFMA attention (R8 structure).  LDS: sp(f32 scores) UNIONED with spb(bf16 P)
// — all threads read their 32 score values into registers before the barrier
// that precedes any spb write.  LDS 51.7 -> ~34.5 KB (4 blocks/CU).
// ---------------------------------------------------------------------------
#define SPW 260
#define SPBW 264
__global__ __launch_bounds__(256) void attn_kernel(
    const u16* __restrict__ qsel, const u16* __restrict__ ksel,
    const float* __restrict__ kbias, const u16* __restrict__ vT,
    u16* __restrict__ ctxJ) {
  const int qt = blockIdx.x, h = blockIdx.y, b = blockIdx.z;
  const int t = threadIdx.x;
  const int w = t >> 6;
  const int lane = t & 63;
  const int m16 = lane & 15;
  const int quad = lane >> 4;

  __shared__ __align__(16) char uni_s[32 * SPW * 4];  // 33.3 KB
  float* sp = (float*)uni_s;
  u16* spb = (u16*)uni_s;
  __shared__ float kb[256];
  __shared__ float inv[32];

  const size_t bh = (size_t)(b * HH + h);
  const int n0 = qt * 32;
  const u16* qg = qsel + (bh * NQ + n0) * KD;
  const u16* kg = ksel + bh * NK * KD;
  const u16* vg = vT + bh * 768 * 256;

  kb[t] = kbias[bh * NK + t];

  f32x4 sacc[2][4];
#pragma unroll
  for (int mt = 0; mt < 2; mt++)
#pragma unroll
    for (int nt = 0; nt < 4; nt++) sacc[mt][nt] = (f32x4)0.f;

  for (int ks = 0; ks < 17; ks++) {
    bf16x8 qa0 = *(const bf16x8*)(qg + (size_t)(0 * 16 + m16) * KD + ks * 32 + quad * 8);
    bf16x8 qa1 = *(const bf16x8*)(qg + (size_t)(1 * 16 + m16) * KD + ks * 32 + quad * 8);
#pragma unroll
    for (int nt = 0; nt < 4; nt++) {
      bf16x8 kf = *(const bf16x8*)(kg + (size_t)(w * 64 + nt * 16 + m16) * KD + ks * 32 + quad * 8);
      sacc[0][nt] = __builtin_amdgcn_mfma_f32_16x16x32_bf16(qa0, kf, sacc[0][nt], 0, 0, 0);
      sacc[1][nt] = __builtin_amdgcn_mfma_f32_16x16x32_bf16(qa1, kf, sacc[1][nt], 0, 0, 0);
    }
  }
#pragma unroll
  for (int mt = 0; mt < 2; mt++)
#pragma unroll
    for (int nt = 0; nt < 4; nt++)
#pragma unroll
      for (int rr = 0; rr < 4; rr++)
        sp[(mt * 16 + quad * 4 + rr) * SPW + w * 64 + nt * 16 + m16] = sacc[mt][nt][rr];
  __syncthreads();

  {
    const int rr = t >> 3, cg = t & 7;
    float vals[32];
    float mx = -1e30f;
#pragma unroll
    for (int i = 0; i < 32; i++) {
      int k = cg + 8 * i;
      float v = sp[rr * SPW + k] + kb[k];
      vals[i] = v;
      mx = fmaxf(mx, v);
    }
    __syncthreads();  // all sp reads done before spb (aliased) writes
#pragma unroll
    for (int off = 4; off; off >>= 1) mx = fmaxf(mx, __shfl_xor(mx, off, 8));
    float s = 0.f;
#pragma unroll
    for (int i = 0; i < 32; i++) {
      float e = __expf(vals[i] - mx);
      s += e;
      spb[rr * SPBW + cg + 8 * i] = f2bf(e);
    }
#pragma unroll
    for (int off = 4; off; off >>= 1) s += __shfl_xor(s, off, 8);
    if (cg == 0) inv[rr] = 1.f / s;
  }
  __syncthreads();

  // ---- PV: D[m=q-row][n=d] ----
  f32x4 oacc[2][12];
#pragma unroll
  for (int mt = 0; mt < 2; mt++)
#pragma unroll
    for (int nt = 0; nt < 12; nt++) oacc[mt][nt] = (f32x4)0.f;

  for (int ks = 0; ks < 8; ks++) {
    bf16x8 pa0 = *(const bf16x8*)(&spb[(0 * 16 + m16) * SPBW + ks * 32 + quad * 8]);
    bf16x8 pa1 = *(const bf16x8*)(&spb[(1 * 16 + m16) * SPBW + ks * 32 + quad * 8]);
#pragma unroll
    for (int nt = 0; nt < 12; nt++) {
      const int d = w * 192 + nt * 16 + m16;
      bf16x8 vf = *(const bf16x8*)(vg + (size_t)d * 256 + ks * 32 + quad * 8);
      oacc[0][nt] = __builtin_amdgcn_mfma_f32_16x16x32_bf16(pa0, vf, oacc[0][nt], 0, 0, 0);
      oacc[1][nt] = __builtin_amdgcn_mfma_f32_16x16x32_bf16(pa1, vf, oacc[1][nt], 0, 0, 0);
    }
  }
  const size_t rowbase = (size_t)b * NQ + n0;
#pragma unroll
  for (int mt = 0; mt < 2; mt++)
#pragma unroll
    for (int rr = 0; rr < 4; rr++) {
      const int row = mt * 16 + quad * 4 + rr;
      const float iv = inv[row];
      u32 pk[6];
#pragma unroll
      for (int j = 0; j < 6; j++) {
        u32 lo = f2bf(oacc[mt][2 * j][rr] * iv);
        u32 hi = f2bf(oacc[mt][2 * j + 1][rr] * iv);
        pk[j] = lo | (hi << 16);
      }
      u16* dst = ctxJ + ((size_t)m16 * 8192 + rowbase + row) * 384 + h * 48 + w * 12;
#pragma unroll
      for (int q3 = 0; q3 < 3; q3++) {
        uint2 uv = {pk[2 * q3], pk[2 * q3 + 1]};
        *(uint2*)(dst + q3 * 4) = uv;
      }
    }
}

// ---------------------------------------------------------------------------
// out_kernel v4 (MFMA, R8-proven): block 1024 = 16 waves (wave = component).
// ---------------------------------------------------------------------------
#define ESTR2 785
__global__ __launch_bounds__(1024) void out_kernel(
    const u16* __restrict__ ctxJ, const u16* __restrict__ WoB,
    const float* __restrict__ bo, const float* __restrict__ hidden,
    float* __restrict__ out) {
  __shared__ __align__(16) float es[16 * ESTR2];  // 50.2 KB
  const int t = threadIdx.x;
  const int c = __builtin_amdgcn_readfirstlane(t >> 6);
  const int lane = t & 63;
  const int m16 = lane & 15, quad = lane >> 4;
  const int row0 = blockIdx.x * 32;
  const int g = grade_of(c);
  const u16* wb = WoB + (size_t)g * 48 * 384;

  for (int ch = 0; ch < 2; ch++) {
    const int r0 = row0 + ch * 16;
    f32x4 acc[3];
#pragma unroll
    for (int nt = 0; nt < 3; nt++) acc[nt] = (f32x4)0.f;
    const u16* ap = ctxJ + ((size_t)c * 8192 + r0 + m16) * 384 + quad * 8;
#pragma unroll 4
    for (int ks = 0; ks < 12; ks++) {
      bf16x8 af = *(const bf16x8*)(ap + ks * 32);
#pragma unroll
      for (int nt = 0; nt < 3; nt++) {
        bf16x8 bf = *(const bf16x8*)(wb + (size_t)(nt * 16 + m16) * 384 + ks * 32 + quad * 8);
        acc[nt] = __builtin_amdgcn_mfma_f32_16x16x32_bf16(af, bf, acc[nt], 0, 0, 0);
      }
    }
    __syncthreads();
#pragma unroll
    for (int nt = 0; nt < 3; nt++)
#pragma unroll
      for (int rr = 0; rr < 4; rr++)
        es[(quad * 4 + rr) * ESTR2 + c * 49 + nt * 16 + m16] = acc[nt][rr];
    __syncthreads();
#pragma unroll
    for (int k = 0; k < 3; k++) {
      int m4 = t + 1024 * k;
      int r = m4 / 192;
      int col0 = (m4 - r * 192) * 4;
      int o = col0 >> 4, cb = col0 & 15;
      const float* er = &es[r * ESTR2 + o];
      float4 v;
      v.x = er[(cb + 0) * 49];
      v.y = er[(cb + 1) * 49];
      v.z = er[(cb + 2) * 49];
      v.w = er[(cb + 3) * 49];
      if (cb == 0) v.x += bo[o];
      size_t gidx = (size_t)(r0 + r) * 768 + col0;
      const float4 hv = *(const float4*)&hidden[gidx];
      v.x += hv.x; v.y += hv.y; v.z += hv.z; v.w += hv.w;
      *(float4*)&out[gidx] = v;
    }
  }
}

// ---------------------------------------------------------------------------
extern "C" void kernel_launch(void* const* d_in, const int* in_sizes, int n_in,
                              void* d_out, int out_size, void* d_ws, size_t ws_size,
                              hipStream_t stream) {
  const float* hidden = (const float*)d_in[0];
  const float* vis = (const float*)d_in[1];
  const float* lnw = (const float*)d_in[2];
  const float* Wq = (const float*)d_in[3];
  const float* bq = (const float*)d_in[4];
  const float* Wkv = (const float*)d_in[5];
  const float* bkv = (const float*)d_in[6];
  const float* Wo = (const float*)d_in[7];
  const float* bo = (const float*)d_in[8];
  const float* daa = (const float*)d_in[9];
  float* out = (float*)d_out;

  char* ws = (char*)d_ws;
  size_t off = 0;
  auto carve = [&](size_t bytes) -> void* {
    void* p = ws + off;
    off += (bytes + 255) & ~(size_t)255;
    return p;
  };
  float* rscale = (float*)carve((size_t)BB * NQ * 4);
  u16* WqB = (u16*)carve((size_t)5 * 384 * 64 * 2);
  u16* WkvB = (u16*)carve((size_t)5 * 768 * 64 * 2);
  u16* WoB = (u16*)carve((size_t)5 * 48 * 384 * 2);
  u16* qsel = (u16*)carve((size_t)BB * HH * NQ * KD * 2);
  u16* ksel = (u16*)carve((size_t)BB * HH * NK * KD * 2);
  u16* vT = (u16*)carve((size_t)BB * HH * 768 * 256 * 2);
  float* kbias = (float*)carve((size_t)BB * HH * NK * 4);
  // union: [xq | xv] consumed by q/kv, then ctxJ overwrites
  char* uni = (char*)carve((size_t)16 * 384 * 8192 * 2);  // 100.7 MB
  u16* ctxJ = (u16*)uni;
  u16* xq = (u16*)uni;                                      // 16 MB
  u16* xv = (u16*)(uni + (size_t)16 * 8192 * 64 * 2);       // 4 MB

  rms_kernel<<<BB * NQ / 32, 256, 0, stream>>>(hidden, rscale);
  wB_kernel<<<1800, 256, 0, stream>>>(Wq, Wkv, Wo, WqB, WkvB, WoB);
  xJ_kernel<<<BB * NQ / 64, 256, 0, stream>>>(hidden, xq, rscale, lnw, BB * NQ, 1);
  xJ_kernel<<<BB * NK / 64, 256, 0, stream>>>(vis, xv, nullptr, nullptr, BB * NK, 0);
  kv_mfma<<<dim3(BB * NK / 64, 27), 256, 0, stream>>>(xv, WkvB, bkv, ksel, vT);
  k2_kernel<<<64, 256, 0, stream>>>(ksel, daa, kbias);
  q_mfma<<<dim3(BB * NQ / 64, 11), 256, 0, stream>>>(xq, WqB, bq, daa, qsel);
  attn_kernel<<<dim3(NQ / 32, HH, BB), 256, 0, stream>>>(qsel, ksel, kbias, vT, ctxJ);
  out_kernel<<<256, 1024, 0, stream>>>(ctxJ, WoB, bo, hidden, out);
}